// Round 4
// baseline (514.105 us; speedup 1.0000x reference)
//
#include <hip/hip_runtime.h>
#include <hip/hip_cooperative_groups.h>
#include <stdint.h>

namespace cg = cooperative_groups;

#define NNODES 50000
#define NEDGES 800000
#define NB ((NNODES + 255) / 256)          // 196 dst-buckets (dst>>8); nodes align to buckets
#define EPB 4096                           // edges per block in build phases

typedef __attribute__((ext_vector_type(8))) short bf16x8;
typedef __attribute__((ext_vector_type(4))) float f32x4;

__device__ inline unsigned short f2bf(float f) {
    unsigned u = __float_as_uint(f);
    return (unsigned short)((u + 0x7fffu + ((u >> 16) & 1u)) >> 16);
}
__device__ inline float bf2f(unsigned short h) {
    return __uint_as_float(((unsigned)h) << 16);
}

// ---------------- weight repack element: W[K][M] fp32 -> split-bf16 frag order ----
__device__ inline void repack_elem(const float* __restrict__ W, unsigned short* __restrict__ hi,
                                   unsigned short* __restrict__ lo, int K, int M, int i) {
    const int k = i / M, n = i % M;
    const int KS = K / 32;
    const int cb = n >> 7;
    const int ct = (n >> 4) & 7;
    const int ln = ((k >> 3) & 3) * 16 + (n & 15);
    const int j  = k & 7;
    const int ks = k >> 5;
    const size_t o = ((((size_t)cb * KS + ks) * 8 + ct) * 64 + ln) * 8 + j;
    const float f = W[i];
    const unsigned short h = f2bf(f);
    hi[o] = h;
    lo[o] = f2bf(f - bf2f(h));
}

// ---------------- cooperative build kernel ----------------
// One dispatch replacing: repack x2, zero, bucket_count, bucket_scan,
// bucket_scatter, csr_fill(+cvt).  196 blocks, 4 grid syncs.
// src < 65536 so an edge packs as (dst&255)<<16 | src in one uint32.
__global__ __launch_bounds__(256) void build_kernel(const int* __restrict__ src,
                                                    const int* __restrict__ dst,
                                                    const float* __restrict__ W1,
                                                    const float* __restrict__ W2,
                                                    unsigned short* __restrict__ W1hi,
                                                    unsigned short* __restrict__ W1lo,
                                                    unsigned short* __restrict__ W2hi,
                                                    unsigned short* __restrict__ W2lo,
                                                    int* __restrict__ bhist,
                                                    int* __restrict__ gcur,
                                                    unsigned* __restrict__ gpk,
                                                    int* __restrict__ rp,
                                                    float* __restrict__ dinv,
                                                    unsigned short* __restrict__ col,
                                                    const float* __restrict__ x,
                                                    unsigned short* __restrict__ xbf) {
    __shared__ int h[256];
    __shared__ int s[256];
    __shared__ int aux[256];
    __shared__ float sdv[256];
    __shared__ unsigned pr[EPB];
    __shared__ int ga[EPB];

    cg::grid_group grid = cg::this_grid();
    const int t = threadIdx.x;
    const int b = blockIdx.x;
    const int NT = gridDim.x * 256;
    const int gtid = b * 256 + t;

    // ---- phase 0: weight repack + zero bhist ----
    for (int i = gtid; i < 128 * 256; i += NT) repack_elem(W1, W1hi, W1lo, 128, 256, i);
    for (int i = gtid; i < 256 * 128; i += NT) repack_elem(W2, W2hi, W2lo, 256, 128, i);
    if (b == 0 && t < NB) bhist[t] = 0;
    __threadfence();
    grid.sync();

    // ---- phase 1: bucket count (block b -> edges [b*EPB, b*EPB+EPB)) ----
    h[t] = 0;
    __syncthreads();
    const int base = b * EPB;
#pragma unroll
    for (int i = 0; i < EPB / 256; ++i) {
        const int e = base + t + i * 256;
        if (e < NEDGES) atomicAdd(&h[dst[e] >> 8], 1);
    }
    __syncthreads();
    if (t < NB && h[t]) atomicAdd(&bhist[t], h[t]);
    __threadfence();
    grid.sync();

    // ---- phase 2: scan (every block redundantly; block 0 publishes gcur) ----
    s[t] = (t < NB) ? bhist[t] : 0;
    __syncthreads();
    for (int off = 1; off < 256; off <<= 1) {
        int v = (t >= off) ? s[t - off] : 0;
        __syncthreads();
        s[t] += v;
        __syncthreads();
    }
    const int my_beg = (b > 0) ? s[b - 1] : 0;   // this block's bucket range (phase 4)
    const int my_end = s[b];
    if (b == 0) {
        if (t < NB) gcur[t] = (t > 0) ? s[t - 1] : 0;
        if (t == 255) rp[NNODES] = s[255];
    }
    __threadfence();
    grid.sync();

    // ---- phase 3: scatter into bucket-ordered gpk ----
    const int nval = min(EPB, NEDGES - base);
    h[t] = 0;
    __syncthreads();
#pragma unroll
    for (int i = 0; i < EPB / 256; ++i) {
        const int e = base + t + i * 256;
        if (e < NEDGES) atomicAdd(&h[dst[e] >> 8], 1);
    }
    __syncthreads();
    s[t] = h[t];
    __syncthreads();
    for (int off = 1; off < 256; off <<= 1) {
        int v = (t >= off) ? s[t - off] : 0;
        __syncthreads();
        s[t] += v;
        __syncthreads();
    }
    {
        const int c = h[t];
        if (t < NB && c > 0) aux[t] = atomicAdd(&gcur[t], c);
        const int lofs = s[t] - c;
        h[t] = lofs;
        s[t] = lofs;
    }
    __syncthreads();
#pragma unroll
    for (int i = 0; i < EPB / 256; ++i) {
        const int e = base + t + i * 256;
        if (e < NEDGES) {
            const int d = dst[e];
            const int bb = d >> 8;
            const int slot = atomicAdd(&h[bb], 1);
            pr[slot] = ((unsigned)(d & 255) << 16) | (unsigned)src[e];
            ga[slot] = aux[bb] + (slot - s[bb]);
        }
    }
    __syncthreads();
#pragma unroll
    for (int i = 0; i < EPB / 256; ++i) {
        const int slot = t + i * 256;
        if (slot < nval) gpk[ga[slot]] = pr[slot];
    }
    __threadfence();
    grid.sync();

    // ---- phase 4: per-bucket degree hist + scan -> rp/dinv, col fill, + cvt ----
    h[t] = 0;
    __syncthreads();
    for (int e = my_beg + t; e < my_end; e += 256) atomicAdd(&h[gpk[e] >> 16], 1);
    __syncthreads();
    s[t] = h[t];
    __syncthreads();
    for (int off = 1; off < 256; off <<= 1) {
        int v = (t >= off) ? s[t - off] : 0;
        __syncthreads();
        s[t] += v;
        __syncthreads();
    }
    const int excl = s[t] - h[t];
    aux[t] = excl;
    const int node = b * 256 + t;
    const float dv = rsqrtf((float)(h[t] + 1));   // +1 self loop
    sdv[t] = dv;
    if (node < NNODES) {
        rp[node] = my_beg + excl;
        dinv[node] = dv;
    }
    __syncthreads();
    for (int e = my_beg + t; e < my_end; e += 256) {
        const unsigned p = gpk[e];
        const int r = atomicAdd(&aux[p >> 16], 1);
        col[my_beg + r] = (unsigned short)(p & 0xffffu);
    }
    // fused cvt: x -> premultiplied bf16 mirror for this bucket's rows
    const int nrows = min(256, NNODES - b * 256);
    const float* xb = x + (size_t)b * 256 * 128;
    unsigned short* ob = xbf + (size_t)b * 256 * 128;
    const int n4 = nrows * 32;                     // 32 float4-groups per 128-row
    for (int i = t; i < n4; i += 256) {
        const float dv2 = sdv[i >> 5];
        float4 v = *(const float4*)(xb + (size_t)i * 4);
        ushort4 hh;
        hh.x = f2bf(dv2 * v.x); hh.y = f2bf(dv2 * v.y);
        hh.z = f2bf(dv2 * v.z); hh.w = f2bf(dv2 * v.w);
        *(ushort4*)(ob + (size_t)i * 4) = hh;
    }
}

// ---------------- gather aggregation (premultiplied mirrors) ----------------
// out[d] = dinv[d] * ( dinv[d]*in32[d] + sum_s mirror[s] ) [+bias][relu]
// F=128: wave per dst; QUARTER-wave (16 lanes x 16B) per edge -> 4 edges in
// flight per step; 4-deep unroll -> up to 16 gathers in flight per wave.

template <bool RELU, bool HAS_BIAS>
__global__ __launch_bounds__(256) void agg128_kernel(const float* __restrict__ in32,
                                                     const unsigned short* __restrict__ inbf,
                                                     float* __restrict__ out,
                                                     const int* __restrict__ rp,
                                                     const unsigned short* __restrict__ col,
                                                     const float* __restrict__ dinv,
                                                     const float* __restrict__ bias) {
    const int wave = threadIdx.x >> 6;
    const int lane = threadIdx.x & 63;
    const int d = blockIdx.x * 4 + wave;
    if (d >= NNODES) return;
    const int quarter = lane >> 4;   // 0..3 : which edge of a group of 4
    const int fl = lane & 15;        // 16 lanes x 8 features = 128
    const float dv = dinv[d];

    float acc[8] = {0.f, 0.f, 0.f, 0.f, 0.f, 0.f, 0.f, 0.f};
    if (quarter == 0) {
        float4 s0 = *(const float4*)(in32 + (size_t)d * 128 + fl * 8);
        float4 s1 = *(const float4*)(in32 + (size_t)d * 128 + fl * 8 + 4);
        acc[0] = dv * s0.x; acc[1] = dv * s0.y; acc[2] = dv * s0.z; acc[3] = dv * s0.w;
        acc[4] = dv * s1.x; acc[5] = dv * s1.y; acc[6] = dv * s1.z; acc[7] = dv * s1.w;
    }

    int j = rp[d] + quarter;
    const int end = rp[d + 1];
    // 4-deep: 16 edges per wave per iteration
    for (; j + 12 < end; j += 16) {
        const int c0 = col[j], c1 = col[j + 4], c2 = col[j + 8], c3 = col[j + 12];
        bf16x8 a0 = *(const bf16x8*)(inbf + (size_t)c0 * 128 + fl * 8);
        bf16x8 a1 = *(const bf16x8*)(inbf + (size_t)c1 * 128 + fl * 8);
        bf16x8 a2 = *(const bf16x8*)(inbf + (size_t)c2 * 128 + fl * 8);
        bf16x8 a3 = *(const bf16x8*)(inbf + (size_t)c3 * 128 + fl * 8);
#pragma unroll
        for (int k = 0; k < 8; ++k)
            acc[k] += (bf2f((unsigned short)a0[k]) + bf2f((unsigned short)a1[k])) +
                      (bf2f((unsigned short)a2[k]) + bf2f((unsigned short)a3[k]));
    }
    // 2-deep tail
    for (; j + 4 < end; j += 8) {
        const int c0 = col[j], c1 = col[j + 4];
        bf16x8 a0 = *(const bf16x8*)(inbf + (size_t)c0 * 128 + fl * 8);
        bf16x8 a1 = *(const bf16x8*)(inbf + (size_t)c1 * 128 + fl * 8);
#pragma unroll
        for (int k = 0; k < 8; ++k)
            acc[k] += bf2f((unsigned short)a0[k]) + bf2f((unsigned short)a1[k]);
    }
    if (j < end) {
        const int c0 = col[j];
        bf16x8 a0 = *(const bf16x8*)(inbf + (size_t)c0 * 128 + fl * 8);
#pragma unroll
        for (int k = 0; k < 8; ++k) acc[k] += bf2f((unsigned short)a0[k]);
    }

#pragma unroll
    for (int v = 0; v < 8; ++v) {
        acc[v] += __shfl_down(acc[v], 32);
        acc[v] += __shfl_down(acc[v], 16);
    }

    if (quarter == 0) {
        float r[8];
#pragma unroll
        for (int v = 0; v < 8; ++v) {
            float t = dv * acc[v];
            if constexpr (HAS_BIAS) t += bias[fl * 8 + v];
            if constexpr (RELU) t = fmaxf(t, 0.0f);
            r[v] = t;
        }
        *(float4*)(out + (size_t)d * 128 + fl * 8)     = make_float4(r[0], r[1], r[2], r[3]);
        *(float4*)(out + (size_t)d * 128 + fl * 8 + 4) = make_float4(r[4], r[5], r[6], r[7]);
    }
}

// F=64: wave per dst; EIGHTH-wave (8 lanes x 16B = one 128B line) per edge ->
// 8 edges in flight per step; 2-deep unroll -> 16 gathers in flight per wave.
// Optional premultiplied bf16 mirror of the OUTPUT (for a following aggregate-first layer).
template <bool RELU, bool HAS_BIAS, bool WRITE_BF>
__global__ __launch_bounds__(256) void agg64_kernel(const float* __restrict__ in32,
                                                    const unsigned short* __restrict__ inbf,
                                                    float* __restrict__ out,
                                                    unsigned short* __restrict__ outbf,
                                                    const int* __restrict__ rp,
                                                    const unsigned short* __restrict__ col,
                                                    const float* __restrict__ dinv,
                                                    const float* __restrict__ bias) {
    const int wave = threadIdx.x >> 6;
    const int lane = threadIdx.x & 63;
    const int d = blockIdx.x * 4 + wave;
    if (d >= NNODES) return;
    const int eighth = lane >> 3;    // 0..7 : which edge of a group of 8
    const int fl = lane & 7;         // 8 lanes x 8 features = 64
    const float dv = dinv[d];

    float acc[8] = {0.f, 0.f, 0.f, 0.f, 0.f, 0.f, 0.f, 0.f};
    if (eighth == 0) {
        float4 s0 = *(const float4*)(in32 + (size_t)d * 64 + fl * 8);
        float4 s1 = *(const float4*)(in32 + (size_t)d * 64 + fl * 8 + 4);
        acc[0] = dv * s0.x; acc[1] = dv * s0.y; acc[2] = dv * s0.z; acc[3] = dv * s0.w;
        acc[4] = dv * s1.x; acc[5] = dv * s1.y; acc[6] = dv * s1.z; acc[7] = dv * s1.w;
    }

    int j = rp[d] + eighth;
    const int end = rp[d + 1];
    for (; j + 8 < end; j += 16) {
        const int c0 = col[j], c1 = col[j + 8];
        bf16x8 a0 = *(const bf16x8*)(inbf + (size_t)c0 * 64 + fl * 8);
        bf16x8 a1 = *(const bf16x8*)(inbf + (size_t)c1 * 64 + fl * 8);
#pragma unroll
        for (int k = 0; k < 8; ++k)
            acc[k] += bf2f((unsigned short)a0[k]) + bf2f((unsigned short)a1[k]);
    }
    if (j < end) {
        const int c0 = col[j];
        bf16x8 a0 = *(const bf16x8*)(inbf + (size_t)c0 * 64 + fl * 8);
#pragma unroll
        for (int k = 0; k < 8; ++k) acc[k] += bf2f((unsigned short)a0[k]);
    }

#pragma unroll
    for (int v = 0; v < 8; ++v) {
        acc[v] += __shfl_down(acc[v], 32);
        acc[v] += __shfl_down(acc[v], 16);
        acc[v] += __shfl_down(acc[v], 8);
    }

    if (eighth == 0) {
        float r[8];
#pragma unroll
        for (int v = 0; v < 8; ++v) {
            float t = dv * acc[v];
            if constexpr (HAS_BIAS) t += bias[fl * 8 + v];
            if constexpr (RELU) t = fmaxf(t, 0.0f);
            r[v] = t;
        }
        *(float4*)(out + (size_t)d * 64 + fl * 8)     = make_float4(r[0], r[1], r[2], r[3]);
        *(float4*)(out + (size_t)d * 64 + fl * 8 + 4) = make_float4(r[4], r[5], r[6], r[7]);
        if constexpr (WRITE_BF) {
            ushort4 h0, h1;
            h0.x = f2bf(dv * r[0]); h0.y = f2bf(dv * r[1]);
            h0.z = f2bf(dv * r[2]); h0.w = f2bf(dv * r[3]);
            h1.x = f2bf(dv * r[4]); h1.y = f2bf(dv * r[5]);
            h1.z = f2bf(dv * r[6]); h1.w = f2bf(dv * r[7]);
            *(ushort4*)(outbf + (size_t)d * 64 + fl * 8)     = h0;
            *(ushort4*)(outbf + (size_t)d * 64 + fl * 8 + 4) = h1;
        }
    }
}

// ---------------- split-bf16 MFMA GEMM (round-1 proven form) ----------------
// BM=64: 4 waves in 1x4, each 64x32. bf mirror premultiplied by dinv[row].

template <int K, int M, int BM, bool BIAS_RELU, bool WRITE_BF>
__global__ __launch_bounds__(256) void mfma_gemm_kernel(const float* __restrict__ A,
                                                        const unsigned short* __restrict__ Whi,
                                                        const unsigned short* __restrict__ Wlo,
                                                        const float* __restrict__ bias,
                                                        float* __restrict__ C,
                                                        unsigned short* __restrict__ Cbf,
                                                        const float* __restrict__ dinv) {
    constexpr int KS = K / 32;
    constexpr int ASZ = BM * 64;
    constexpr int CI = (BM == 128) ? 4 : 2;
    __shared__ char lds[2 * ASZ + 16384];
    char* Ahi = lds;
    char* Alo = lds + ASZ;
    char* Bhi = lds + 2 * ASZ;
    char* Blo = lds + 2 * ASZ + 8192;

    const int t = threadIdx.x;
    const int lane = t & 63;
    const int w = t >> 6;
    const int wr = (BM == 128) ? (w >> 1) : 0;
    const int wc = (BM == 128) ? (w & 1) : w;
    const int r0 = blockIdx.x * BM;
    const int n0 = blockIdx.y * 128;

    const unsigned short* bhg = Whi + (size_t)blockIdx.y * KS * 4096;
    const unsigned short* blg = Wlo + (size_t)blockIdx.y * KS * 4096;

    f32x4 acc[4][CI];
#pragma unroll
    for (int i = 0; i < 4; ++i)
#pragma unroll
        for (int j = 0; j < CI; ++j) acc[i][j] = (f32x4){0.f, 0.f, 0.f, 0.f};

    for (int ks = 0; ks < KS; ++ks) {
        const int k0 = ks * 32;

        {
            const char* gh = (const char*)(bhg + (size_t)ks * 4096);
            const char* gl = (const char*)(blg + (size_t)ks * 4096);
#pragma unroll
            for (int c = 0; c < 2; ++c) {
                const int ct = w * 2 + c;
                __builtin_amdgcn_global_load_lds(
                    (const __attribute__((address_space(1))) void*)(gh + ct * 1024 + lane * 16),
                    (__attribute__((address_space(3))) void*)(Bhi + ct * 1024), 16, 0, 0);
                __builtin_amdgcn_global_load_lds(
                    (const __attribute__((address_space(1))) void*)(gl + ct * 1024 + lane * 16),
                    (__attribute__((address_space(3))) void*)(Blo + ct * 1024), 16, 0, 0);
            }
        }

        float4 av[BM / 32];
#pragma unroll
        for (int i = 0; i < BM / 32; ++i) {
            const int q = t + i * 256;
            const int row = q >> 3;
            const int kq = (q & 7) * 4;
            const int gr = r0 + row;
            float4 v = make_float4(0.f, 0.f, 0.f, 0.f);
            if (gr < NNODES) v = *(const float4*)(A + (size_t)gr * K + k0 + kq);
            av[i] = v;
        }
#pragma unroll
        for (int i = 0; i < BM / 32; ++i) {
            const int q = t + i * 256;
            const int row = q >> 3;
            const int kq = (q & 7) * 4;
            const int rt = row >> 4, m = row & 15, quad = kq >> 3, j0 = kq & 7;
            const int off = rt * 1024 + (quad * 16 + m) * 16 + j0 * 2;
            const float4 v = av[i];
            ushort4 h, l;
            h.x = f2bf(v.x); l.x = f2bf(v.x - bf2f(h.x));
            h.y = f2bf(v.y); l.y = f2bf(v.y - bf2f(h.y));
            h.z = f2bf(v.z); l.z = f2bf(v.z - bf2f(h.z));
            h.w = f2bf(v.w); l.w = f2bf(v.w - bf2f(h.w));
            *(ushort4*)(Ahi + off) = h;
            *(ushort4*)(Alo + off) = l;
        }
        __syncthreads();

        bf16x8 ah[4], al[4], bh[CI], bl[CI];
#pragma unroll
        for (int i = 0; i < 4; ++i) {
            ah[i] = *(const bf16x8*)(Ahi + (wr * 4 + i) * 1024 + lane * 16);
            al[i] = *(const bf16x8*)(Alo + (wr * 4 + i) * 1024 + lane * 16);
        }
#pragma unroll
        for (int j = 0; j < CI; ++j) {
            bh[j] = *(const bf16x8*)(Bhi + (wc * CI + j) * 1024 + lane * 16);
            bl[j] = *(const bf16x8*)(Blo + (wc * CI + j) * 1024 + lane * 16);
        }
#pragma unroll
        for (int i = 0; i < 4; ++i)
#pragma unroll
            for (int j = 0; j < CI; ++j) {
                acc[i][j] = __builtin_amdgcn_mfma_f32_16x16x32_bf16(ah[i], bh[j], acc[i][j], 0, 0, 0);
                acc[i][j] = __builtin_amdgcn_mfma_f32_16x16x32_bf16(ah[i], bl[j], acc[i][j], 0, 0, 0);
                acc[i][j] = __builtin_amdgcn_mfma_f32_16x16x32_bf16(al[i], bh[j], acc[i][j], 0, 0, 0);
            }
        __syncthreads();
    }

    const int quad = lane >> 4;
    const int cl = lane & 15;
#pragma unroll
    for (int i = 0; i < 4; ++i) {
#pragma unroll
        for (int j = 0; j < CI; ++j) {
            const int colg = n0 + wc * (CI * 16) + j * 16 + cl;
            float bv = 0.f;
            if constexpr (BIAS_RELU) bv = bias[colg];
#pragma unroll
            for (int r = 0; r < 4; ++r) {
                const int rowg = r0 + wr * 64 + i * 16 + quad * 4 + r;
                if (rowg < NNODES) {
                    float v = acc[i][j][r] + bv;
                    if constexpr (BIAS_RELU) v = fmaxf(v, 0.f);
                    C[(size_t)rowg * M + colg] = v;
                    if constexpr (WRITE_BF) Cbf[(size_t)rowg * M + colg] = f2bf(dinv[rowg] * v);
                }
            }
        }
    }
}

// ---------------- fp32 register-tiled GEMM ----------------

template <int BM, int BN, int BK, int TM, int TN, bool HAS_BIAS, bool RELU, bool WRITE_BF>
__global__ __launch_bounds__(256) void gemm_kernel(const float* __restrict__ A,
                                                   const float* __restrict__ W,
                                                   const float* __restrict__ bias,
                                                   float* __restrict__ C,
                                                   unsigned short* __restrict__ Cbf,
                                                   const float* __restrict__ dinv,
                                                   int Nrows, int K, int M) {
    constexpr int TX = BN / TN;
    constexpr int TY = BM / TM;
    static_assert(TX * TY == 256, "thread grid must be 256");
    constexpr int A_LOADS = (BM * BK) / (256 * 4);
    constexpr int W_LOADS = (BN * BK) / (256 * 4);
    static_assert(A_LOADS >= 1 && W_LOADS >= 1, "tile too small");

    const int tid = threadIdx.x;
    const int tx = tid % TX;
    const int ty = tid / TX;
    const int r0 = blockIdx.x * BM;
    const int c0 = blockIdx.y * BN;

    __shared__ float As[BK][BM + 4];
    __shared__ float Ws[BK][BN];

    float acc[TM][TN] = {};

    for (int k0 = 0; k0 < K; k0 += BK) {
#pragma unroll
        for (int l = 0; l < A_LOADS; ++l) {
            const int idx = tid + l * 256;
            const int row = idx / (BK / 4);
            const int kq = idx % (BK / 4);
            float4 v = make_float4(0.f, 0.f, 0.f, 0.f);
            const int gr = r0 + row;
            if (gr < Nrows) v = *(const float4*)(A + (size_t)gr * K + k0 + kq * 4);
            As[kq * 4 + 0][row] = v.x;
            As[kq * 4 + 1][row] = v.y;
            As[kq * 4 + 2][row] = v.z;
            As[kq * 4 + 3][row] = v.w;
        }
#pragma unroll
        for (int l = 0; l < W_LOADS; ++l) {
            const int idx = tid + l * 256;
            const int kk = idx / (BN / 4);
            const int cq = idx % (BN / 4);
            const int gc = c0 + cq * 4;
            float4 v;
            const float* wrow = W + (size_t)(k0 + kk) * M;
            if (gc + 3 < M) {
                v = *(const float4*)(wrow + gc);
            } else {
                v.x = (gc + 0 < M) ? wrow[gc + 0] : 0.f;
                v.y = (gc + 1 < M) ? wrow[gc + 1] : 0.f;
                v.z = (gc + 2 < M) ? wrow[gc + 2] : 0.f;
                v.w = (gc + 3 < M) ? wrow[gc + 3] : 0.f;
            }
            *(float4*)&Ws[kk][cq * 4] = v;
        }
        __syncthreads();

#pragma unroll
        for (int kk = 0; kk < BK; ++kk) {
            float a[TM], b[TN];
#pragma unroll
            for (int i = 0; i < TM; ++i) a[i] = As[kk][ty * TM + i];
#pragma unroll
            for (int j = 0; j < TN; ++j) b[j] = Ws[kk][tx * TN + j];
#pragma unroll
            for (int i = 0; i < TM; ++i)
#pragma unroll
                for (int j = 0; j < TN; ++j) acc[i][j] += a[i] * b[j];
        }
        __syncthreads();
    }

#pragma unroll
    for (int i = 0; i < TM; ++i) {
        const int gr = r0 + ty * TM + i;
        if (gr >= Nrows) continue;
        const float dvr = WRITE_BF ? dinv[gr] : 0.f;
#pragma unroll
        for (int j = 0; j < TN; ++j) {
            const int gc = c0 + tx * TN + j;
            if (gc >= M) continue;
            float v = acc[i][j];
            if constexpr (HAS_BIAS) v += bias[gc];
            if constexpr (RELU) v = fmaxf(v, 0.0f);
            C[(size_t)gr * M + gc] = v;
            if constexpr (WRITE_BF) Cbf[(size_t)gr * M + gc] = f2bf(dvr * v);
        }
    }
}

// ---------------- launch ----------------

extern "C" void kernel_launch(void* const* d_in, const int* in_sizes, int n_in,
                              void* d_out, int out_size, void* d_ws, size_t ws_size,
                              hipStream_t stream) {
    const float* x  = (const float*)d_in[0];
    const int* ei   = (const int*)d_in[1];
    const float* W1 = (const float*)d_in[2];
    const float* b1 = (const float*)d_in[3];
    const float* W2 = (const float*)d_in[4];
    const float* b2 = (const float*)d_in[5];
    const float* W3 = (const float*)d_in[6];
    const float* b3 = (const float*)d_in[7];
    const float* W4 = (const float*)d_in[8];
    const float* b4 = (const float*)d_in[9];
    float* out = (float*)d_out;
    const int* esrc = ei;
    const int* edst = ei + NEDGES;

    char* w = (char*)d_ws;
    auto alloc = [&](size_t bytes) -> void* {
        void* p = (void*)w;
        w += (bytes + 255) & ~(size_t)255;
        return p;
    };
    int* rp     = (int*)alloc((size_t)(NNODES + 1) * 4);
    unsigned short* col = (unsigned short*)alloc((size_t)NEDGES * 2);
    float* dinv = (float*)alloc((size_t)NNODES * 4);
    int* bhist  = (int*)alloc((size_t)NB * 4);
    int* gcur   = (int*)alloc((size_t)NB * 4);
    unsigned* gpk = (unsigned*)alloc((size_t)NEDGES * 4);
    unsigned short* W1hi = (unsigned short*)alloc((size_t)128 * 256 * 2);
    unsigned short* W1lo = (unsigned short*)alloc((size_t)128 * 256 * 2);
    unsigned short* W2hi = (unsigned short*)alloc((size_t)256 * 128 * 2);
    unsigned short* W2lo = (unsigned short*)alloc((size_t)256 * 128 * 2);
    float* B0   = (float*)alloc((size_t)NNODES * 256 * 4);
    float* B1   = (float*)alloc((size_t)NNODES * 128 * 4);
    float* B2   = (float*)alloc((size_t)NNODES * 128 * 4);
    unsigned short* xbf  = (unsigned short*)alloc((size_t)NNODES * 128 * 2);
    unsigned short* B1bf = (unsigned short*)alloc((size_t)NNODES * 128 * 2);
    unsigned short* B0bf = (unsigned short*)alloc((size_t)NNODES * 64 * 2);   // premult t3 mirror
    unsigned short* B3bf = (unsigned short*)alloc((size_t)NNODES * 64 * 2);   // premult h3 mirror

    // CSR build + weight repack + x-mirror cvt: ONE cooperative dispatch
    {
        void* args[] = {(void*)&esrc, (void*)&edst, (void*)&W1, (void*)&W2,
                        (void*)&W1hi, (void*)&W1lo, (void*)&W2hi, (void*)&W2lo,
                        (void*)&bhist, (void*)&gcur, (void*)&gpk,
                        (void*)&rp, (void*)&dinv, (void*)&col, (void*)&x, (void*)&xbf};
        hipLaunchCooperativeKernel((void*)build_kernel, dim3(NB), dim3(256), args, 0, stream);
    }

    const int aggGrid = (NNODES + 3) / 4;
    const int rowBlks64 = (NNODES + 63) / 64;   // 782

    // Layer 1: aggregate first (dim 128), then MFMA GEMM 128->256 (+bias+relu)
    agg128_kernel<false, false><<<aggGrid, 256, 0, stream>>>(x, xbf, B2, rp, col, dinv, nullptr);
    mfma_gemm_kernel<128, 256, 64, true, false>
        <<<dim3(rowBlks64, 2), 256, 0, stream>>>(B2, W1hi, W1lo, b1, B0, nullptr, nullptr);

    // Layer 2: MFMA GEMM 256->128 (emit premult bf16 mirror), then aggregate (+bias+relu)
    mfma_gemm_kernel<256, 128, 64, false, true>
        <<<dim3(rowBlks64, 1), 256, 0, stream>>>(B0, W2hi, W2lo, nullptr, B1, B1bf, dinv);
    agg128_kernel<true, true><<<aggGrid, 256, 0, stream>>>(B1, B1bf, B2, rp, col, dinv, b2);

    // Layer 3: fp32 GEMM 128->64 (emit premult t3 mirror), aggregate (+bias+relu, emit premult h3 mirror)
    gemm_kernel<64, 64, 16, 4, 4, false, false, true>
        <<<dim3(rowBlks64, 1), 256, 0, stream>>>(B2, W3, nullptr, B0, B0bf, dinv, NNODES, 128, 64);
    agg64_kernel<true, true, true><<<aggGrid, 256, 0, stream>>>(B0, B0bf, B1, B3bf, rp, col, dinv, b3);

    // Layer 4 (aggregate-first via linearity): pure agg64 on h3, then GEMM 64->40 (+bias) -> out
    agg64_kernel<false, false, false><<<aggGrid, 256, 0, stream>>>(B1, B3bf, B2, nullptr, rp, col, dinv, nullptr);
    gemm_kernel<64, 64, 16, 4, 4, true, false, false>
        <<<dim3(rowBlks64, 1), 256, 0, stream>>>(B2, W4, b4, out, nullptr, nullptr, NNODES, 64, 40);
}

// Round 5
// 358.386 us; speedup vs baseline: 1.4345x; 1.4345x over previous
//
#include <hip/hip_runtime.h>
#include <stdint.h>

#define NNODES 50000
#define NEDGES 800000
#define NB ((NNODES + 255) / 256)          // 196 dst-buckets (dst>>8); nodes align to buckets
#define EPB 4096                           // edges per scatter block
#define SCAT_NBLK ((NEDGES + EPB - 1) / EPB)  // 196

typedef __attribute__((ext_vector_type(8))) short bf16x8;
typedef __attribute__((ext_vector_type(4))) float f32x4;

__device__ inline unsigned short f2bf(float f) {
    unsigned u = __float_as_uint(f);
    return (unsigned short)((u + 0x7fffu + ((u >> 16) & 1u)) >> 16);
}
__device__ inline float bf2f(unsigned short h) {
    return __uint_as_float(((unsigned)h) << 16);
}

// ---------------- bucketed CSR build ----------------
// src < 65536 so an edge packs as (dst&255)<<16 | src in one uint32; col stored as ushort.

__global__ void zero_kernel(int* __restrict__ p, int n) {
    int i = blockIdx.x * blockDim.x + threadIdx.x;
    if (i < n) p[i] = 0;
}

__global__ __launch_bounds__(256) void bucket_count_kernel(const int* __restrict__ dst,
                                                           int* __restrict__ bhist) {
    __shared__ int h[NB];
    for (int b = threadIdx.x; b < NB; b += 256) h[b] = 0;
    __syncthreads();
    const int base = blockIdx.x * EPB;
#pragma unroll
    for (int i = 0; i < EPB / 256; ++i) {
        const int e = base + threadIdx.x + i * 256;
        if (e < NEDGES) atomicAdd(&h[dst[e] >> 8], 1);
    }
    __syncthreads();
    for (int b = threadIdx.x; b < NB; b += 256)
        if (h[b]) atomicAdd(&bhist[b], h[b]);
}

__global__ __launch_bounds__(256) void bucket_scan_kernel(const int* __restrict__ bhist,
                                                          int* __restrict__ bofs,
                                                          int* __restrict__ gcur,
                                                          int* __restrict__ rp_last) {
    __shared__ int s[256];
    const int t = threadIdx.x;
    s[t] = (t < NB) ? bhist[t] : 0;
    __syncthreads();
    for (int off = 1; off < 256; off <<= 1) {
        int v = (t >= off) ? s[t - off] : 0;
        __syncthreads();
        s[t] += v;
        __syncthreads();
    }
    if (t < NB) {
        const int excl = (t > 0) ? s[t - 1] : 0;
        bofs[t] = excl;
        gcur[t] = excl;
    }
    if (t == 255) { bofs[NB] = s[255]; rp_last[0] = s[255]; }
}

__global__ __launch_bounds__(256) void bucket_scatter_kernel(const int* __restrict__ src,
                                                             const int* __restrict__ dst,
                                                             int* __restrict__ gcur,
                                                             unsigned* __restrict__ gpk) {
    __shared__ int h[256];
    __shared__ int s[256];
    __shared__ int gof[256];
    __shared__ unsigned pr[EPB];
    __shared__ int ga[EPB];

    const int t = threadIdx.x;
    const int base = blockIdx.x * EPB;
    const int nval = min(EPB, NEDGES - base);

    h[t] = 0;
    __syncthreads();
#pragma unroll
    for (int i = 0; i < EPB / 256; ++i) {
        const int e = base + t + i * 256;
        if (e < NEDGES) atomicAdd(&h[dst[e] >> 8], 1);
    }
    __syncthreads();
    s[t] = h[t];
    __syncthreads();
    for (int off = 1; off < 256; off <<= 1) {
        int v = (t >= off) ? s[t - off] : 0;
        __syncthreads();
        s[t] += v;
        __syncthreads();
    }
    {
        const int c = h[t];
        if (t < NB && c > 0) gof[t] = atomicAdd(&gcur[t], c);
        const int lofs = s[t] - c;
        h[t] = lofs;
        s[t] = lofs;
    }
    __syncthreads();
#pragma unroll
    for (int i = 0; i < EPB / 256; ++i) {
        const int e = base + t + i * 256;
        if (e < NEDGES) {
            const int d = dst[e];
            const int b = d >> 8;
            const int slot = atomicAdd(&h[b], 1);
            pr[slot] = ((unsigned)(d & 255) << 16) | (unsigned)src[e];
            ga[slot] = gof[b] + (slot - s[b]);
        }
    }
    __syncthreads();
#pragma unroll
    for (int i = 0; i < EPB / 256; ++i) {
        const int slot = t + i * 256;
        if (slot < nval) gpk[ga[slot]] = pr[slot];
    }
}

// Pass 4: per-bucket degree hist + scan -> rp/dinv, col fill (16-bit col).
// FUSED: also emits the premultiplied bf16 mirror xbf = bf16(dinv[row]*x[row])
// for this bucket's 256 rows (dinv just computed in-block).
__global__ __launch_bounds__(256) void csr_fill_kernel(const unsigned* __restrict__ gpk,
                                                       const int* __restrict__ bofs,
                                                       int* __restrict__ rp,
                                                       float* __restrict__ dinv,
                                                       unsigned short* __restrict__ col,
                                                       const float* __restrict__ x,
                                                       unsigned short* __restrict__ xbf) {
    __shared__ int c[256];
    __shared__ int s[256];
    __shared__ int cur[256];
    __shared__ float sdv[256];
    const int t = threadIdx.x;
    const int b = blockIdx.x;
    const int beg = bofs[b], end = bofs[b + 1];
    c[t] = 0;
    __syncthreads();
    for (int e = beg + t; e < end; e += 256) atomicAdd(&c[gpk[e] >> 16], 1);
    __syncthreads();
    s[t] = c[t];
    __syncthreads();
    for (int off = 1; off < 256; off <<= 1) {
        int v = (t >= off) ? s[t - off] : 0;
        __syncthreads();
        s[t] += v;
        __syncthreads();
    }
    const int excl = s[t] - c[t];
    cur[t] = excl;
    const int node = b * 256 + t;
    const float dv = rsqrtf((float)(c[t] + 1));   // +1 self loop
    sdv[t] = dv;
    if (node < NNODES) {
        rp[node] = beg + excl;
        dinv[node] = dv;
    }
    __syncthreads();
    for (int e = beg + t; e < end; e += 256) {
        const unsigned p = gpk[e];
        const int r = atomicAdd(&cur[p >> 16], 1);
        col[beg + r] = (unsigned short)(p & 0xffffu);
    }
    // fused cvt: x -> premultiplied bf16 mirror for this bucket's rows
    const int nrows = min(256, NNODES - b * 256);
    const float* xb = x + (size_t)b * 256 * 128;
    unsigned short* ob = xbf + (size_t)b * 256 * 128;
    const int n4 = nrows * 32;                     // 32 float4-groups per 128-row
    for (int i = t; i < n4; i += 256) {
        const float dv2 = sdv[i >> 5];
        float4 v = *(const float4*)(xb + (size_t)i * 4);
        ushort4 hh;
        hh.x = f2bf(dv2 * v.x); hh.y = f2bf(dv2 * v.y);
        hh.z = f2bf(dv2 * v.z); hh.w = f2bf(dv2 * v.w);
        *(ushort4*)(ob + (size_t)i * 4) = hh;
    }
}

// ---------------- gather aggregation (premultiplied mirrors) ----------------
// out[d] = dinv[d] * ( dinv[d]*in32[d] + sum_s mirror[s] ) [+bias][relu]
// F=128: wave per dst; QUARTER-wave (16 lanes x 16B) per edge -> 4 edges in
// flight per step; 4-deep unroll -> up to 16 gathers in flight per wave.
// WRITE_SPLIT: emit the result as row-major split-bf16 (hi/lo) instead of
// fp32 — feeds the MFMA GEMM's copy-only fragment staging.

template <bool RELU, bool HAS_BIAS, bool WRITE_SPLIT>
__global__ __launch_bounds__(256) void agg128_kernel(const float* __restrict__ in32,
                                                     const unsigned short* __restrict__ inbf,
                                                     float* __restrict__ out,
                                                     unsigned short* __restrict__ outhi,
                                                     unsigned short* __restrict__ outlo,
                                                     const int* __restrict__ rp,
                                                     const unsigned short* __restrict__ col,
                                                     const float* __restrict__ dinv,
                                                     const float* __restrict__ bias) {
    const int wave = threadIdx.x >> 6;
    const int lane = threadIdx.x & 63;
    const int d = blockIdx.x * 4 + wave;
    if (d >= NNODES) return;
    const int quarter = lane >> 4;   // 0..3 : which edge of a group of 4
    const int fl = lane & 15;        // 16 lanes x 8 features = 128
    const float dv = dinv[d];

    float acc[8] = {0.f, 0.f, 0.f, 0.f, 0.f, 0.f, 0.f, 0.f};
    if (quarter == 0) {
        float4 s0 = *(const float4*)(in32 + (size_t)d * 128 + fl * 8);
        float4 s1 = *(const float4*)(in32 + (size_t)d * 128 + fl * 8 + 4);
        acc[0] = dv * s0.x; acc[1] = dv * s0.y; acc[2] = dv * s0.z; acc[3] = dv * s0.w;
        acc[4] = dv * s1.x; acc[5] = dv * s1.y; acc[6] = dv * s1.z; acc[7] = dv * s1.w;
    }

    int j = rp[d] + quarter;
    const int end = rp[d + 1];
    // 4-deep: 16 edges per wave per iteration
    for (; j + 12 < end; j += 16) {
        const int c0 = col[j], c1 = col[j + 4], c2 = col[j + 8], c3 = col[j + 12];
        bf16x8 a0 = *(const bf16x8*)(inbf + (size_t)c0 * 128 + fl * 8);
        bf16x8 a1 = *(const bf16x8*)(inbf + (size_t)c1 * 128 + fl * 8);
        bf16x8 a2 = *(const bf16x8*)(inbf + (size_t)c2 * 128 + fl * 8);
        bf16x8 a3 = *(const bf16x8*)(inbf + (size_t)c3 * 128 + fl * 8);
#pragma unroll
        for (int k = 0; k < 8; ++k)
            acc[k] += (bf2f((unsigned short)a0[k]) + bf2f((unsigned short)a1[k])) +
                      (bf2f((unsigned short)a2[k]) + bf2f((unsigned short)a3[k]));
    }
    // 2-deep tail
    for (; j + 4 < end; j += 8) {
        const int c0 = col[j], c1 = col[j + 4];
        bf16x8 a0 = *(const bf16x8*)(inbf + (size_t)c0 * 128 + fl * 8);
        bf16x8 a1 = *(const bf16x8*)(inbf + (size_t)c1 * 128 + fl * 8);
#pragma unroll
        for (int k = 0; k < 8; ++k)
            acc[k] += bf2f((unsigned short)a0[k]) + bf2f((unsigned short)a1[k]);
    }
    if (j < end) {
        const int c0 = col[j];
        bf16x8 a0 = *(const bf16x8*)(inbf + (size_t)c0 * 128 + fl * 8);
#pragma unroll
        for (int k = 0; k < 8; ++k) acc[k] += bf2f((unsigned short)a0[k]);
    }

#pragma unroll
    for (int v = 0; v < 8; ++v) {
        acc[v] += __shfl_down(acc[v], 32);
        acc[v] += __shfl_down(acc[v], 16);
    }

    if (quarter == 0) {
        float r[8];
#pragma unroll
        for (int v = 0; v < 8; ++v) {
            float t = dv * acc[v];
            if constexpr (HAS_BIAS) t += bias[fl * 8 + v];
            if constexpr (RELU) t = fmaxf(t, 0.0f);
            r[v] = t;
        }
        if constexpr (WRITE_SPLIT) {
            ushort4 h0, h1v, l0, l1v;
            h0.x = f2bf(r[0]); l0.x = f2bf(r[0] - bf2f(h0.x));
            h0.y = f2bf(r[1]); l0.y = f2bf(r[1] - bf2f(h0.y));
            h0.z = f2bf(r[2]); l0.z = f2bf(r[2] - bf2f(h0.z));
            h0.w = f2bf(r[3]); l0.w = f2bf(r[3] - bf2f(h0.w));
            h1v.x = f2bf(r[4]); l1v.x = f2bf(r[4] - bf2f(h1v.x));
            h1v.y = f2bf(r[5]); l1v.y = f2bf(r[5] - bf2f(h1v.y));
            h1v.z = f2bf(r[6]); l1v.z = f2bf(r[6] - bf2f(h1v.z));
            h1v.w = f2bf(r[7]); l1v.w = f2bf(r[7] - bf2f(h1v.w));
            *(ushort4*)(outhi + (size_t)d * 128 + fl * 8)     = h0;
            *(ushort4*)(outhi + (size_t)d * 128 + fl * 8 + 4) = h1v;
            *(ushort4*)(outlo + (size_t)d * 128 + fl * 8)     = l0;
            *(ushort4*)(outlo + (size_t)d * 128 + fl * 8 + 4) = l1v;
        } else {
            *(float4*)(out + (size_t)d * 128 + fl * 8)     = make_float4(r[0], r[1], r[2], r[3]);
            *(float4*)(out + (size_t)d * 128 + fl * 8 + 4) = make_float4(r[4], r[5], r[6], r[7]);
        }
    }
}

// F=64: wave per dst; EIGHTH-wave (8 lanes x 16B = one 128B line) per edge ->
// 8 edges in flight per step; 2-deep unroll -> 16 gathers in flight per wave.
// Optional premultiplied bf16 mirror of the OUTPUT (for a following aggregate-first layer).
template <bool RELU, bool HAS_BIAS, bool WRITE_BF>
__global__ __launch_bounds__(256) void agg64_kernel(const float* __restrict__ in32,
                                                    const unsigned short* __restrict__ inbf,
                                                    float* __restrict__ out,
                                                    unsigned short* __restrict__ outbf,
                                                    const int* __restrict__ rp,
                                                    const unsigned short* __restrict__ col,
                                                    const float* __restrict__ dinv,
                                                    const float* __restrict__ bias) {
    const int wave = threadIdx.x >> 6;
    const int lane = threadIdx.x & 63;
    const int d = blockIdx.x * 4 + wave;
    if (d >= NNODES) return;
    const int eighth = lane >> 3;    // 0..7 : which edge of a group of 8
    const int fl = lane & 7;         // 8 lanes x 8 features = 64
    const float dv = dinv[d];

    float acc[8] = {0.f, 0.f, 0.f, 0.f, 0.f, 0.f, 0.f, 0.f};
    if (eighth == 0) {
        float4 s0 = *(const float4*)(in32 + (size_t)d * 64 + fl * 8);
        float4 s1 = *(const float4*)(in32 + (size_t)d * 64 + fl * 8 + 4);
        acc[0] = dv * s0.x; acc[1] = dv * s0.y; acc[2] = dv * s0.z; acc[3] = dv * s0.w;
        acc[4] = dv * s1.x; acc[5] = dv * s1.y; acc[6] = dv * s1.z; acc[7] = dv * s1.w;
    }

    int j = rp[d] + eighth;
    const int end = rp[d + 1];
    for (; j + 8 < end; j += 16) {
        const int c0 = col[j], c1 = col[j + 8];
        bf16x8 a0 = *(const bf16x8*)(inbf + (size_t)c0 * 64 + fl * 8);
        bf16x8 a1 = *(const bf16x8*)(inbf + (size_t)c1 * 64 + fl * 8);
#pragma unroll
        for (int k = 0; k < 8; ++k)
            acc[k] += bf2f((unsigned short)a0[k]) + bf2f((unsigned short)a1[k]);
    }
    if (j < end) {
        const int c0 = col[j];
        bf16x8 a0 = *(const bf16x8*)(inbf + (size_t)c0 * 64 + fl * 8);
#pragma unroll
        for (int k = 0; k < 8; ++k) acc[k] += bf2f((unsigned short)a0[k]);
    }

#pragma unroll
    for (int v = 0; v < 8; ++v) {
        acc[v] += __shfl_down(acc[v], 32);
        acc[v] += __shfl_down(acc[v], 16);
        acc[v] += __shfl_down(acc[v], 8);
    }

    if (eighth == 0) {
        float r[8];
#pragma unroll
        for (int v = 0; v < 8; ++v) {
            float t = dv * acc[v];
            if constexpr (HAS_BIAS) t += bias[fl * 8 + v];
            if constexpr (RELU) t = fmaxf(t, 0.0f);
            r[v] = t;
        }
        *(float4*)(out + (size_t)d * 64 + fl * 8)     = make_float4(r[0], r[1], r[2], r[3]);
        *(float4*)(out + (size_t)d * 64 + fl * 8 + 4) = make_float4(r[4], r[5], r[6], r[7]);
        if constexpr (WRITE_BF) {
            ushort4 h0, h1;
            h0.x = f2bf(dv * r[0]); h0.y = f2bf(dv * r[1]);
            h0.z = f2bf(dv * r[2]); h0.w = f2bf(dv * r[3]);
            h1.x = f2bf(dv * r[4]); h1.y = f2bf(dv * r[5]);
            h1.z = f2bf(dv * r[6]); h1.w = f2bf(dv * r[7]);
            *(ushort4*)(outbf + (size_t)d * 64 + fl * 8)     = h0;
            *(ushort4*)(outbf + (size_t)d * 64 + fl * 8 + 4) = h1;
        }
    }
}

// ---------------- weight repack: W[K][M] fp32 -> split-bf16 fragment order ----

template <int K, int M>
__global__ __launch_bounds__(256) void repack_kernel(const float* __restrict__ W,
                                                     unsigned short* __restrict__ hi,
                                                     unsigned short* __restrict__ lo) {
    int i = blockIdx.x * 256 + threadIdx.x;
    if (i >= K * M) return;
    const int k = i / M, n = i % M;
    constexpr int KS = K / 32;
    const int cb = n >> 7;
    const int ct = (n >> 4) & 7;
    const int ln = ((k >> 3) & 3) * 16 + (n & 15);
    const int j  = k & 7;
    const int ks = k >> 5;
    const size_t o = ((((size_t)cb * KS + ks) * 8 + ct) * 64 + ln) * 8 + j;
    const float f = W[i];
    const unsigned short h = f2bf(f);
    hi[o] = h;
    lo[o] = f2bf(f - bf2f(h));
}

// ---------------- split-bf16 MFMA GEMM, copy-only A staging ----------------
// Round-1 proven loop structure (reg-staged A -> LDS frag layout, B via
// global_load_lds, 2 barriers/K-step) but A arrives as row-major split-bf16
// from the producer: staging is a pure ushort4 copy — the ~80 VALU/thread/step
// f2bf conversion chain is gone from the GEMM hot loop.
// BM=64, 4 waves in 1x4; wave w owns cols [n0+w*32, n0+w*32+32).
// EPI=0: +bias, relu, write row-major split-bf16 (chains into next GEMM).
// EPI=1: write fp32 C + premultiplied bf16 mirror (feeds aggregation).

template <int K, int M, int EPI>
__global__ __launch_bounds__(256) void mfma_sb_kernel(const unsigned short* __restrict__ Ahi_g,
                                                      const unsigned short* __restrict__ Alo_g,
                                                      const unsigned short* __restrict__ Whi,
                                                      const unsigned short* __restrict__ Wlo,
                                                      const float* __restrict__ bias,
                                                      float* __restrict__ C,
                                                      unsigned short* __restrict__ Chi,
                                                      unsigned short* __restrict__ Clo,
                                                      unsigned short* __restrict__ Cbf,
                                                      const float* __restrict__ dinv) {
    constexpr int KS = K / 32;
    constexpr int CI = 2;
    __shared__ char lds[8192 + 16384];
    char* Ahi = lds;              // 4 KB: 64 rows x 32 k (hi)
    char* Alo = lds + 4096;       // 4 KB (lo)
    char* Bhi = lds + 8192;       // 8 KB
    char* Blo = lds + 16384;      // 8 KB

    const int t = threadIdx.x;
    const int lane = t & 63;
    const int w = t >> 6;
    const int r0 = blockIdx.x * 64;
    const int n0 = blockIdx.y * 128;

    const unsigned short* bhg = Whi + (size_t)blockIdx.y * KS * 4096;
    const unsigned short* blg = Wlo + (size_t)blockIdx.y * KS * 4096;

    f32x4 acc[4][CI];
#pragma unroll
    for (int i = 0; i < 4; ++i)
#pragma unroll
        for (int j = 0; j < CI; ++j) acc[i][j] = (f32x4){0.f, 0.f, 0.f, 0.f};

    for (int ks = 0; ks < KS; ++ks) {
        const int k0 = ks * 32;

        {
            const char* gh = (const char*)(bhg + (size_t)ks * 4096);
            const char* gl = (const char*)(blg + (size_t)ks * 4096);
#pragma unroll
            for (int c = 0; c < 2; ++c) {
                const int ct = w * 2 + c;
                __builtin_amdgcn_global_load_lds(
                    (const __attribute__((address_space(1))) void*)(gh + ct * 1024 + lane * 16),
                    (__attribute__((address_space(3))) void*)(Bhi + ct * 1024), 16, 0, 0);
                __builtin_amdgcn_global_load_lds(
                    (const __attribute__((address_space(1))) void*)(gl + ct * 1024 + lane * 16),
                    (__attribute__((address_space(3))) void*)(Blo + ct * 1024), 16, 0, 0);
            }
        }

        // A staging: pure copy of producer-written split-bf16 (8 elems/thread)
        ushort4 hv[2], lv[2];
#pragma unroll
        for (int i = 0; i < 2; ++i) {
            const int q = t + i * 256;
            const int row = q >> 3;
            const int kq = (q & 7) * 4;
            const int gr = r0 + row;
            ushort4 h = {0, 0, 0, 0}, l = {0, 0, 0, 0};
            if (gr < NNODES) {
                h = *(const ushort4*)(Ahi_g + (size_t)gr * K + k0 + kq);
                l = *(const ushort4*)(Alo_g + (size_t)gr * K + k0 + kq);
            }
            hv[i] = h;
            lv[i] = l;
        }
#pragma unroll
        for (int i = 0; i < 2; ++i) {
            const int q = t + i * 256;
            const int row = q >> 3;
            const int kq = (q & 7) * 4;
            const int rt = row >> 4, m = row & 15, quad = kq >> 3, j0 = kq & 7;
            const int off = rt * 1024 + (quad * 16 + m) * 16 + j0 * 2;
            *(ushort4*)(Ahi + off) = hv[i];
            *(ushort4*)(Alo + off) = lv[i];
        }
        __syncthreads();

        bf16x8 ah[4], al[4], bh[CI], bl[CI];
#pragma unroll
        for (int i = 0; i < 4; ++i) {
            ah[i] = *(const bf16x8*)(Ahi + i * 1024 + lane * 16);
            al[i] = *(const bf16x8*)(Alo + i * 1024 + lane * 16);
        }
#pragma unroll
        for (int j = 0; j < CI; ++j) {
            bh[j] = *(const bf16x8*)(Bhi + (w * CI + j) * 1024 + lane * 16);
            bl[j] = *(const bf16x8*)(Blo + (w * CI + j) * 1024 + lane * 16);
        }
#pragma unroll
        for (int i = 0; i < 4; ++i)
#pragma unroll
            for (int j = 0; j < CI; ++j) {
                acc[i][j] = __builtin_amdgcn_mfma_f32_16x16x32_bf16(ah[i], bh[j], acc[i][j], 0, 0, 0);
                acc[i][j] = __builtin_amdgcn_mfma_f32_16x16x32_bf16(ah[i], bl[j], acc[i][j], 0, 0, 0);
                acc[i][j] = __builtin_amdgcn_mfma_f32_16x16x32_bf16(al[i], bh[j], acc[i][j], 0, 0, 0);
            }
        __syncthreads();
    }

    const int quad = lane >> 4;
    const int cl = lane & 15;
#pragma unroll
    for (int i = 0; i < 4; ++i) {
#pragma unroll
        for (int j = 0; j < CI; ++j) {
            const int colg = n0 + w * (CI * 16) + j * 16 + cl;
            float bv = 0.f;
            if constexpr (EPI == 0) bv = bias[colg];
#pragma unroll
            for (int r = 0; r < 4; ++r) {
                const int rowg = r0 + i * 16 + quad * 4 + r;
                if (rowg < NNODES) {
                    if constexpr (EPI == 0) {
                        const float v = fmaxf(acc[i][j][r] + bv, 0.f);
                        const unsigned short h = f2bf(v);
                        Chi[(size_t)rowg * M + colg] = h;
                        Clo[(size_t)rowg * M + colg] = f2bf(v - bf2f(h));
                    } else {
                        const float v = acc[i][j][r];
                        C[(size_t)rowg * M + colg] = v;
                        Cbf[(size_t)rowg * M + colg] = f2bf(dinv[rowg] * v);
                    }
                }
            }
        }
    }
}

// ---------------- fp32 register-tiled GEMM ----------------

template <int BM, int BN, int BK, int TM, int TN, bool HAS_BIAS, bool RELU, bool WRITE_BF>
__global__ __launch_bounds__(256) void gemm_kernel(const float* __restrict__ A,
                                                   const float* __restrict__ W,
                                                   const float* __restrict__ bias,
                                                   float* __restrict__ C,
                                                   unsigned short* __restrict__ Cbf,
                                                   const float* __restrict__ dinv,
                                                   int Nrows, int K, int M) {
    constexpr int TX = BN / TN;
    constexpr int TY = BM / TM;
    static_assert(TX * TY == 256, "thread grid must be 256");
    constexpr int A_LOADS = (BM * BK) / (256 * 4);
    constexpr int W_LOADS = (BN * BK) / (256 * 4);
    static_assert(A_LOADS >= 1 && W_LOADS >= 1, "tile too small");

    const int tid = threadIdx.x;
    const int tx = tid % TX;
    const int ty = tid / TX;
    const int r0 = blockIdx.x * BM;
    const int c0 = blockIdx.y * BN;

    __shared__ float As[BK][BM + 4];
    __shared__ float Ws[BK][BN];

    float acc[TM][TN] = {};

    for (int k0 = 0; k0 < K; k0 += BK) {
#pragma unroll
        for (int l = 0; l < A_LOADS; ++l) {
            const int idx = tid + l * 256;
            const int row = idx / (BK / 4);
            const int kq = idx % (BK / 4);
            float4 v = make_float4(0.f, 0.f, 0.f, 0.f);
            const int gr = r0 + row;
            if (gr < Nrows) v = *(const float4*)(A + (size_t)gr * K + k0 + kq * 4);
            As[kq * 4 + 0][row] = v.x;
            As[kq * 4 + 1][row] = v.y;
            As[kq * 4 + 2][row] = v.z;
            As[kq * 4 + 3][row] = v.w;
        }
#pragma unroll
        for (int l = 0; l < W_LOADS; ++l) {
            const int idx = tid + l * 256;
            const int kk = idx / (BN / 4);
            const int cq = idx % (BN / 4);
            const int gc = c0 + cq * 4;
            float4 v;
            const float* wrow = W + (size_t)(k0 + kk) * M;
            if (gc + 3 < M) {
                v = *(const float4*)(wrow + gc);
            } else {
                v.x = (gc + 0 < M) ? wrow[gc + 0] : 0.f;
                v.y = (gc + 1 < M) ? wrow[gc + 1] : 0.f;
                v.z = (gc + 2 < M) ? wrow[gc + 2] : 0.f;
                v.w = (gc + 3 < M) ? wrow[gc + 3] : 0.f;
            }
            *(float4*)&Ws[kk][cq * 4] = v;
        }
        __syncthreads();

#pragma unroll
        for (int kk = 0; kk < BK; ++kk) {
            float a[TM], b[TN];
#pragma unroll
            for (int i = 0; i < TM; ++i) a[i] = As[kk][ty * TM + i];
#pragma unroll
            for (int j = 0; j < TN; ++j) b[j] = Ws[kk][tx * TN + j];
#pragma unroll
            for (int i = 0; i < TM; ++i)
#pragma unroll
                for (int j = 0; j < TN; ++j) acc[i][j] += a[i] * b[j];
        }
        __syncthreads();
    }

#pragma unroll
    for (int i = 0; i < TM; ++i) {
        const int gr = r0 + ty * TM + i;
        if (gr >= Nrows) continue;
        const float dvr = WRITE_BF ? dinv[gr] : 0.f;
#pragma unroll
        for (int j = 0; j < TN; ++j) {
            const int gc = c0 + tx * TN + j;
            if (gc >= M) continue;
            float v = acc[i][j];
            if constexpr (HAS_BIAS) v += bias[gc];
            if constexpr (RELU) v = fmaxf(v, 0.0f);
            C[(size_t)gr * M + gc] = v;
            if constexpr (WRITE_BF) Cbf[(size_t)gr * M + gc] = f2bf(dvr * v);
        }
    }
}

// ---------------- launch ----------------

extern "C" void kernel_launch(void* const* d_in, const int* in_sizes, int n_in,
                              void* d_out, int out_size, void* d_ws, size_t ws_size,
                              hipStream_t stream) {
    const float* x  = (const float*)d_in[0];
    const int* ei   = (const int*)d_in[1];
    const float* W1 = (const float*)d_in[2];
    const float* b1 = (const float*)d_in[3];
    const float* W2 = (const float*)d_in[4];
    const float* b2 = (const float*)d_in[5];
    const float* W3 = (const float*)d_in[6];
    const float* b3 = (const float*)d_in[7];
    const float* W4 = (const float*)d_in[8];
    const float* b4 = (const float*)d_in[9];
    float* out = (float*)d_out;
    const int* esrc = ei;
    const int* edst = ei + NEDGES;

    char* w = (char*)d_ws;
    auto alloc = [&](size_t bytes) -> void* {
        void* p = (void*)w;
        w += (bytes + 255) & ~(size_t)255;
        return p;
    };
    int* rp     = (int*)alloc((size_t)(NNODES + 1) * 4);
    unsigned short* col = (unsigned short*)alloc((size_t)NEDGES * 2);
    float* dinv = (float*)alloc((size_t)NNODES * 4);
    int* bhist  = (int*)alloc((size_t)NB * 4);
    int* bofs   = (int*)alloc((size_t)(NB + 1) * 4);
    int* gcur   = (int*)alloc((size_t)NB * 4);
    unsigned* gpk = (unsigned*)alloc((size_t)NEDGES * 4);
    unsigned short* W1hi = (unsigned short*)alloc((size_t)128 * 256 * 2);
    unsigned short* W1lo = (unsigned short*)alloc((size_t)128 * 256 * 2);
    unsigned short* W2hi = (unsigned short*)alloc((size_t)256 * 128 * 2);
    unsigned short* W2lo = (unsigned short*)alloc((size_t)256 * 128 * 2);
    // row-major split-bf16 activation mirrors
    unsigned short* AggHi = (unsigned short*)alloc((size_t)NNODES * 128 * 2);
    unsigned short* AggLo = (unsigned short*)alloc((size_t)NNODES * 128 * 2);
    unsigned short* H1hi  = (unsigned short*)alloc((size_t)NNODES * 256 * 2);
    unsigned short* H1lo  = (unsigned short*)alloc((size_t)NNODES * 256 * 2);
    float* B0   = (float*)alloc((size_t)NNODES * 64 * 4);    // fp32 gemm3 out
    float* B1   = (float*)alloc((size_t)NNODES * 128 * 4);
    float* B2   = (float*)alloc((size_t)NNODES * 128 * 4);
    unsigned short* xbf  = (unsigned short*)alloc((size_t)NNODES * 128 * 2);
    unsigned short* B1bf = (unsigned short*)alloc((size_t)NNODES * 128 * 2);
    unsigned short* B0bf = (unsigned short*)alloc((size_t)NNODES * 64 * 2);   // premult t3 mirror
    unsigned short* B3bf = (unsigned short*)alloc((size_t)NNODES * 64 * 2);   // premult h3 mirror

    // weight repack (tiny, independent)
    repack_kernel<128, 256><<<(128 * 256 + 255) / 256, 256, 0, stream>>>(W1, W1hi, W1lo);
    repack_kernel<256, 128><<<(256 * 128 + 255) / 256, 256, 0, stream>>>(W2, W2hi, W2lo);

    // bucketed CSR build (5 dispatches) — produces rp, col16, dinv, xbf
    zero_kernel<<<1, 256, 0, stream>>>(bhist, NB);
    bucket_count_kernel<<<SCAT_NBLK, 256, 0, stream>>>(edst, bhist);
    bucket_scan_kernel<<<1, 256, 0, stream>>>(bhist, bofs, gcur, rp + NNODES);
    bucket_scatter_kernel<<<SCAT_NBLK, 256, 0, stream>>>(esrc, edst, gcur, gpk);
    csr_fill_kernel<<<NB, 256, 0, stream>>>(gpk, bofs, rp, dinv, col, x, xbf);

    const int aggGrid = (NNODES + 3) / 4;
    const int rowBlks64 = (NNODES + 63) / 64;   // 782

    // Layer 1 front: aggregate x (dim 128) -> row-major split-bf16
    agg128_kernel<false, false, true><<<aggGrid, 256, 0, stream>>>(
        x, xbf, nullptr, AggHi, AggLo, rp, col, dinv, nullptr);
    // Layer 1 GEMM: h1 = relu(agg @ W1 + b1) -> row-major split-bf16
    mfma_sb_kernel<128, 256, 0><<<dim3(rowBlks64, 2), 256, 0, stream>>>(
        AggHi, AggLo, W1hi, W1lo, b1, nullptr, H1hi, H1lo, nullptr, nullptr);
    // Layer 2 GEMM: t2 = h1 @ W2 -> fp32 + premultiplied bf16 mirror
    mfma_sb_kernel<256, 128, 1><<<dim3(rowBlks64, 1), 256, 0, stream>>>(
        H1hi, H1lo, W2hi, W2lo, nullptr, B1, nullptr, nullptr, B1bf, dinv);
    // Layer 2 back: aggregate t2 (+bias+relu)
    agg128_kernel<true, true, false><<<aggGrid, 256, 0, stream>>>(
        B1, B1bf, B2, nullptr, nullptr, rp, col, dinv, b2);

    // Layer 3: fp32 GEMM 128->64 (emit premult t3 mirror), aggregate (+bias+relu, emit premult h3 mirror)
    gemm_kernel<64, 64, 16, 4, 4, false, false, true>
        <<<dim3(rowBlks64, 1), 256, 0, stream>>>(B2, W3, nullptr, B0, B0bf, dinv, NNODES, 128, 64);
    agg64_kernel<true, true, true><<<aggGrid, 256, 0, stream>>>(B0, B0bf, B1, B3bf, rp, col, dinv, b3);

    // Layer 4 (aggregate-first via linearity): pure agg64 on h3, then GEMM 64->40 (+bias) -> out
    agg64_kernel<false, false, false><<<aggGrid, 256, 0, stream>>>(B1, B3bf, B2, nullptr, rp, col, dinv, nullptr);
    gemm_kernel<64, 64, 16, 4, 4, true, false, false>
        <<<dim3(rowBlks64, 1), 256, 0, stream>>>(B2, W4, b4, out, nullptr, nullptr, NNODES, 64, 40);
}

// Round 6
// 345.600 us; speedup vs baseline: 1.4876x; 1.0370x over previous
//
#include <hip/hip_runtime.h>
#include <stdint.h>

#define NNODES 50000
#define NEDGES 800000
#define NB ((NNODES + 255) / 256)          // 196 dst-buckets (dst>>8); nodes align to buckets
#define EPB 4096                           // edges per scatter block
#define SCAT_NBLK ((NEDGES + EPB - 1) / EPB)  // 196

typedef __attribute__((ext_vector_type(8))) short bf16x8;
typedef __attribute__((ext_vector_type(4))) float f32x4;

__device__ inline unsigned short f2bf(float f) {
    unsigned u = __float_as_uint(f);
    return (unsigned short)((u + 0x7fffu + ((u >> 16) & 1u)) >> 16);
}
__device__ inline float bf2f(unsigned short h) {
    return __uint_as_float(((unsigned)h) << 16);
}

// ---------------- prep: weight repack (W1+W2) + bhist zero, one dispatch ----

__device__ inline void repack_elem(const float* __restrict__ W, unsigned short* __restrict__ hi,
                                   unsigned short* __restrict__ lo, int K, int M, int i) {
    const int k = i / M, n = i % M;
    const int KS = K / 32;
    const int cb = n >> 7;
    const int ct = (n >> 4) & 7;
    const int ln = ((k >> 3) & 3) * 16 + (n & 15);
    const int j  = k & 7;
    const int ks = k >> 5;
    const size_t o = ((((size_t)cb * KS + ks) * 8 + ct) * 64 + ln) * 8 + j;
    const float f = W[i];
    const unsigned short h = f2bf(f);
    hi[o] = h;
    lo[o] = f2bf(f - bf2f(h));
}

__global__ __launch_bounds__(256) void prep_kernel(const float* __restrict__ W1,
                                                   const float* __restrict__ W2,
                                                   unsigned short* __restrict__ W1hi,
                                                   unsigned short* __restrict__ W1lo,
                                                   unsigned short* __restrict__ W2hi,
                                                   unsigned short* __restrict__ W2lo,
                                                   int* __restrict__ bhist) {
    const int i = blockIdx.x * 256 + threadIdx.x;
    if (i < 128 * 256) repack_elem(W1, W1hi, W1lo, 128, 256, i);
    else repack_elem(W2, W2hi, W2lo, 256, 128, i - 128 * 256);
    if (i < NB) bhist[i] = 0;
}

// ---------------- bucketed CSR build ----------------
// src < 65536 so an edge packs as (dst&255)<<16 | src in one uint32; col stored as ushort.

__global__ __launch_bounds__(256) void bucket_count_kernel(const int* __restrict__ dst,
                                                           int* __restrict__ bhist) {
    __shared__ int h[NB];
    for (int b = threadIdx.x; b < NB; b += 256) h[b] = 0;
    __syncthreads();
    const int base = blockIdx.x * EPB;
#pragma unroll
    for (int i = 0; i < EPB / 256; ++i) {
        const int e = base + threadIdx.x + i * 256;
        if (e < NEDGES) atomicAdd(&h[dst[e] >> 8], 1);
    }
    __syncthreads();
    for (int b = threadIdx.x; b < NB; b += 256)
        if (h[b]) atomicAdd(&bhist[b], h[b]);
}

__global__ __launch_bounds__(256) void bucket_scan_kernel(const int* __restrict__ bhist,
                                                          int* __restrict__ bofs,
                                                          int* __restrict__ gcur,
                                                          int* __restrict__ rp_last) {
    __shared__ int s[256];
    const int t = threadIdx.x;
    s[t] = (t < NB) ? bhist[t] : 0;
    __syncthreads();
    for (int off = 1; off < 256; off <<= 1) {
        int v = (t >= off) ? s[t - off] : 0;
        __syncthreads();
        s[t] += v;
        __syncthreads();
    }
    if (t < NB) {
        const int excl = (t > 0) ? s[t - 1] : 0;
        bofs[t] = excl;
        gcur[t] = excl;
    }
    if (t == 255) { bofs[NB] = s[255]; rp_last[0] = s[255]; }
}

__global__ __launch_bounds__(256) void bucket_scatter_kernel(const int* __restrict__ src,
                                                             const int* __restrict__ dst,
                                                             int* __restrict__ gcur,
                                                             unsigned* __restrict__ gpk) {
    __shared__ int h[256];
    __shared__ int s[256];
    __shared__ int gof[256];
    __shared__ unsigned pr[EPB];
    __shared__ int ga[EPB];

    const int t = threadIdx.x;
    const int base = blockIdx.x * EPB;
    const int nval = min(EPB, NEDGES - base);

    h[t] = 0;
    __syncthreads();
#pragma unroll
    for (int i = 0; i < EPB / 256; ++i) {
        const int e = base + t + i * 256;
        if (e < NEDGES) atomicAdd(&h[dst[e] >> 8], 1);
    }
    __syncthreads();
    s[t] = h[t];
    __syncthreads();
    for (int off = 1; off < 256; off <<= 1) {
        int v = (t >= off) ? s[t - off] : 0;
        __syncthreads();
        s[t] += v;
        __syncthreads();
    }
    {
        const int c = h[t];
        if (t < NB && c > 0) gof[t] = atomicAdd(&gcur[t], c);
        const int lofs = s[t] - c;
        h[t] = lofs;
        s[t] = lofs;
    }
    __syncthreads();
#pragma unroll
    for (int i = 0; i < EPB / 256; ++i) {
        const int e = base + t + i * 256;
        if (e < NEDGES) {
            const int d = dst[e];
            const int b = d >> 8;
            const int slot = atomicAdd(&h[b], 1);
            pr[slot] = ((unsigned)(d & 255) << 16) | (unsigned)src[e];
            ga[slot] = gof[b] + (slot - s[b]);
        }
    }
    __syncthreads();
#pragma unroll
    for (int i = 0; i < EPB / 256; ++i) {
        const int slot = t + i * 256;
        if (slot < nval) gpk[ga[slot]] = pr[slot];
    }
}

// Pass 4: per-bucket degree hist + scan -> rp/dinv, col fill (16-bit col).
// FUSED: also emits the premultiplied bf16 mirror xbf = bf16(dinv[row]*x[row])
// for this bucket's 256 rows (dinv just computed in-block).
__global__ __launch_bounds__(256) void csr_fill_kernel(const unsigned* __restrict__ gpk,
                                                       const int* __restrict__ bofs,
                                                       int* __restrict__ rp,
                                                       float* __restrict__ dinv,
                                                       unsigned short* __restrict__ col,
                                                       const float* __restrict__ x,
                                                       unsigned short* __restrict__ xbf) {
    __shared__ int c[256];
    __shared__ int s[256];
    __shared__ int cur[256];
    __shared__ float sdv[256];
    const int t = threadIdx.x;
    const int b = blockIdx.x;
    const int beg = bofs[b], end = bofs[b + 1];
    c[t] = 0;
    __syncthreads();
    for (int e = beg + t; e < end; e += 256) atomicAdd(&c[gpk[e] >> 16], 1);
    __syncthreads();
    s[t] = c[t];
    __syncthreads();
    for (int off = 1; off < 256; off <<= 1) {
        int v = (t >= off) ? s[t - off] : 0;
        __syncthreads();
        s[t] += v;
        __syncthreads();
    }
    const int excl = s[t] - c[t];
    cur[t] = excl;
    const int node = b * 256 + t;
    const float dv = rsqrtf((float)(c[t] + 1));   // +1 self loop
    sdv[t] = dv;
    if (node < NNODES) {
        rp[node] = beg + excl;
        dinv[node] = dv;
    }
    __syncthreads();
    for (int e = beg + t; e < end; e += 256) {
        const unsigned p = gpk[e];
        const int r = atomicAdd(&cur[p >> 16], 1);
        col[beg + r] = (unsigned short)(p & 0xffffu);
    }
    // fused cvt: x -> premultiplied bf16 mirror for this bucket's rows
    const int nrows = min(256, NNODES - b * 256);
    const float* xb = x + (size_t)b * 256 * 128;
    unsigned short* ob = xbf + (size_t)b * 256 * 128;
    const int n4 = nrows * 32;                     // 32 float4-groups per 128-row
    for (int i = t; i < n4; i += 256) {
        const float dv2 = sdv[i >> 5];
        float4 v = *(const float4*)(xb + (size_t)i * 4);
        ushort4 hh;
        hh.x = f2bf(dv2 * v.x); hh.y = f2bf(dv2 * v.y);
        hh.z = f2bf(dv2 * v.z); hh.w = f2bf(dv2 * v.w);
        *(ushort4*)(ob + (size_t)i * 4) = hh;
    }
}

// ---------------- gather aggregation (premultiplied mirrors) ----------------
// out[d] = dinv[d] * ( dinv[d]*in32[d] + sum_s mirror[s] ) [+bias][relu]
// F=128: wave per dst; QUARTER-wave (16 lanes x 16B) per edge -> 4 edges in
// flight per step; 4-deep unroll -> up to 16 gathers in flight per wave.

template <bool RELU, bool HAS_BIAS>
__global__ __launch_bounds__(256) void agg128_kernel(const float* __restrict__ in32,
                                                     const unsigned short* __restrict__ inbf,
                                                     float* __restrict__ out,
                                                     const int* __restrict__ rp,
                                                     const unsigned short* __restrict__ col,
                                                     const float* __restrict__ dinv,
                                                     const float* __restrict__ bias) {
    const int wave = threadIdx.x >> 6;
    const int lane = threadIdx.x & 63;
    const int d = blockIdx.x * 4 + wave;
    if (d >= NNODES) return;
    const int quarter = lane >> 4;   // 0..3 : which edge of a group of 4
    const int fl = lane & 15;        // 16 lanes x 8 features = 128
    const float dv = dinv[d];

    float acc[8] = {0.f, 0.f, 0.f, 0.f, 0.f, 0.f, 0.f, 0.f};
    if (quarter == 0) {
        float4 s0 = *(const float4*)(in32 + (size_t)d * 128 + fl * 8);
        float4 s1 = *(const float4*)(in32 + (size_t)d * 128 + fl * 8 + 4);
        acc[0] = dv * s0.x; acc[1] = dv * s0.y; acc[2] = dv * s0.z; acc[3] = dv * s0.w;
        acc[4] = dv * s1.x; acc[5] = dv * s1.y; acc[6] = dv * s1.z; acc[7] = dv * s1.w;
    }

    int j = rp[d] + quarter;
    const int end = rp[d + 1];
    // 4-deep: 16 edges per wave per iteration
    for (; j + 12 < end; j += 16) {
        const int c0 = col[j], c1 = col[j + 4], c2 = col[j + 8], c3 = col[j + 12];
        bf16x8 a0 = *(const bf16x8*)(inbf + (size_t)c0 * 128 + fl * 8);
        bf16x8 a1 = *(const bf16x8*)(inbf + (size_t)c1 * 128 + fl * 8);
        bf16x8 a2 = *(const bf16x8*)(inbf + (size_t)c2 * 128 + fl * 8);
        bf16x8 a3 = *(const bf16x8*)(inbf + (size_t)c3 * 128 + fl * 8);
#pragma unroll
        for (int k = 0; k < 8; ++k)
            acc[k] += (bf2f((unsigned short)a0[k]) + bf2f((unsigned short)a1[k])) +
                      (bf2f((unsigned short)a2[k]) + bf2f((unsigned short)a3[k]));
    }
    // 2-deep tail
    for (; j + 4 < end; j += 8) {
        const int c0 = col[j], c1 = col[j + 4];
        bf16x8 a0 = *(const bf16x8*)(inbf + (size_t)c0 * 128 + fl * 8);
        bf16x8 a1 = *(const bf16x8*)(inbf + (size_t)c1 * 128 + fl * 8);
#pragma unroll
        for (int k = 0; k < 8; ++k)
            acc[k] += bf2f((unsigned short)a0[k]) + bf2f((unsigned short)a1[k]);
    }
    if (j < end) {
        const int c0 = col[j];
        bf16x8 a0 = *(const bf16x8*)(inbf + (size_t)c0 * 128 + fl * 8);
#pragma unroll
        for (int k = 0; k < 8; ++k) acc[k] += bf2f((unsigned short)a0[k]);
    }

#pragma unroll
    for (int v = 0; v < 8; ++v) {
        acc[v] += __shfl_down(acc[v], 32);
        acc[v] += __shfl_down(acc[v], 16);
    }

    if (quarter == 0) {
        float r[8];
#pragma unroll
        for (int v = 0; v < 8; ++v) {
            float t = dv * acc[v];
            if constexpr (HAS_BIAS) t += bias[fl * 8 + v];
            if constexpr (RELU) t = fmaxf(t, 0.0f);
            r[v] = t;
        }
        *(float4*)(out + (size_t)d * 128 + fl * 8)     = make_float4(r[0], r[1], r[2], r[3]);
        *(float4*)(out + (size_t)d * 128 + fl * 8 + 4) = make_float4(r[4], r[5], r[6], r[7]);
    }
}

// F=64: wave per dst; EIGHTH-wave (8 lanes x 16B = one 128B line) per edge ->
// 8 edges in flight per step; 2-deep unroll -> 16 gathers in flight per wave.
// Optional premultiplied bf16 mirror of the OUTPUT (for a following aggregate-first layer).
template <bool RELU, bool HAS_BIAS, bool WRITE_BF>
__global__ __launch_bounds__(256) void agg64_kernel(const float* __restrict__ in32,
                                                    const unsigned short* __restrict__ inbf,
                                                    float* __restrict__ out,
                                                    unsigned short* __restrict__ outbf,
                                                    const int* __restrict__ rp,
                                                    const unsigned short* __restrict__ col,
                                                    const float* __restrict__ dinv,
                                                    const float* __restrict__ bias) {
    const int wave = threadIdx.x >> 6;
    const int lane = threadIdx.x & 63;
    const int d = blockIdx.x * 4 + wave;
    if (d >= NNODES) return;
    const int eighth = lane >> 3;    // 0..7 : which edge of a group of 8
    const int fl = lane & 7;         // 8 lanes x 8 features = 64
    const float dv = dinv[d];

    float acc[8] = {0.f, 0.f, 0.f, 0.f, 0.f, 0.f, 0.f, 0.f};
    if (eighth == 0) {
        float4 s0 = *(const float4*)(in32 + (size_t)d * 64 + fl * 8);
        float4 s1 = *(const float4*)(in32 + (size_t)d * 64 + fl * 8 + 4);
        acc[0] = dv * s0.x; acc[1] = dv * s0.y; acc[2] = dv * s0.z; acc[3] = dv * s0.w;
        acc[4] = dv * s1.x; acc[5] = dv * s1.y; acc[6] = dv * s1.z; acc[7] = dv * s1.w;
    }

    int j = rp[d] + eighth;
    const int end = rp[d + 1];
    for (; j + 8 < end; j += 16) {
        const int c0 = col[j], c1 = col[j + 8];
        bf16x8 a0 = *(const bf16x8*)(inbf + (size_t)c0 * 64 + fl * 8);
        bf16x8 a1 = *(const bf16x8*)(inbf + (size_t)c1 * 64 + fl * 8);
#pragma unroll
        for (int k = 0; k < 8; ++k)
            acc[k] += bf2f((unsigned short)a0[k]) + bf2f((unsigned short)a1[k]);
    }
    if (j < end) {
        const int c0 = col[j];
        bf16x8 a0 = *(const bf16x8*)(inbf + (size_t)c0 * 64 + fl * 8);
#pragma unroll
        for (int k = 0; k < 8; ++k) acc[k] += bf2f((unsigned short)a0[k]);
    }

#pragma unroll
    for (int v = 0; v < 8; ++v) {
        acc[v] += __shfl_down(acc[v], 32);
        acc[v] += __shfl_down(acc[v], 16);
        acc[v] += __shfl_down(acc[v], 8);
    }

    if (eighth == 0) {
        float r[8];
#pragma unroll
        for (int v = 0; v < 8; ++v) {
            float t = dv * acc[v];
            if constexpr (HAS_BIAS) t += bias[fl * 8 + v];
            if constexpr (RELU) t = fmaxf(t, 0.0f);
            r[v] = t;
        }
        *(float4*)(out + (size_t)d * 64 + fl * 8)     = make_float4(r[0], r[1], r[2], r[3]);
        *(float4*)(out + (size_t)d * 64 + fl * 8 + 4) = make_float4(r[4], r[5], r[6], r[7]);
        if constexpr (WRITE_BF) {
            ushort4 h0, h1;
            h0.x = f2bf(dv * r[0]); h0.y = f2bf(dv * r[1]);
            h0.z = f2bf(dv * r[2]); h0.w = f2bf(dv * r[3]);
            h1.x = f2bf(dv * r[4]); h1.y = f2bf(dv * r[5]);
            h1.z = f2bf(dv * r[6]); h1.w = f2bf(dv * r[7]);
            *(ushort4*)(outbf + (size_t)d * 64 + fl * 8)     = h0;
            *(ushort4*)(outbf + (size_t)d * 64 + fl * 8 + 4) = h1;
        }
    }
}

// ---------------- split-bf16 MFMA GEMM (round-1 proven loop, CI=M/64) ----------------
// BM=64, 4 waves; wave w owns col-tiles [w*CI, w*CI+CI) (16 cols each) -> the
// whole M in ONE pass (no grid.y A re-read). A staged fp32->split-bf16 in regs
// (round-1 path); B fragments via global_load_lds from repacked weights.

template <int K, int M, bool BIAS_RELU, bool WRITE_BF>
__global__ __launch_bounds__(256) void mfma_gemm_kernel(const float* __restrict__ A,
                                                        const unsigned short* __restrict__ Whi,
                                                        const unsigned short* __restrict__ Wlo,
                                                        const float* __restrict__ bias,
                                                        float* __restrict__ C,
                                                        unsigned short* __restrict__ Cbf,
                                                        const float* __restrict__ dinv) {
    constexpr int KS = K / 32;
    constexpr int CI = M / 64;            // 16-col tiles per wave
    __shared__ char lds[8192 + 2 * M * 64];
    char* Ahi = lds;                      // 4 KB
    char* Alo = lds + 4096;               // 4 KB
    char* Bhi = lds + 8192;               // M*64 bytes
    char* Blo = lds + 8192 + M * 64;      // M*64 bytes

    const int t = threadIdx.x;
    const int lane = t & 63;
    const int w = t >> 6;
    const int r0 = blockIdx.x * 64;

    f32x4 acc[4][CI];
#pragma unroll
    for (int i = 0; i < 4; ++i)
#pragma unroll
        for (int j = 0; j < CI; ++j) acc[i][j] = (f32x4){0.f, 0.f, 0.f, 0.f};

    for (int ks = 0; ks < KS; ++ks) {
        const int k0 = ks * 32;

        {
#pragma unroll
            for (int c = 0; c < CI; ++c) {
                const int g = w * CI + c;                       // global 16-col tile
                const size_t srcb = ((size_t)((g >> 3) * KS + ks) * 8 + (g & 7)) * 1024;
                __builtin_amdgcn_global_load_lds(
                    (const __attribute__((address_space(1))) void*)((const char*)Whi + srcb + lane * 16),
                    (__attribute__((address_space(3))) void*)(Bhi + g * 1024), 16, 0, 0);
                __builtin_amdgcn_global_load_lds(
                    (const __attribute__((address_space(1))) void*)((const char*)Wlo + srcb + lane * 16),
                    (__attribute__((address_space(3))) void*)(Blo + g * 1024), 16, 0, 0);
            }
        }

        float4 av[2];
#pragma unroll
        for (int i = 0; i < 2; ++i) {
            const int q = t + i * 256;
            const int row = q >> 3;
            const int kq = (q & 7) * 4;
            const int gr = r0 + row;
            float4 v = make_float4(0.f, 0.f, 0.f, 0.f);
            if (gr < NNODES) v = *(const float4*)(A + (size_t)gr * K + k0 + kq);
            av[i] = v;
        }
#pragma unroll
        for (int i = 0; i < 2; ++i) {
            const int q = t + i * 256;
            const int row = q >> 3;
            const int kq = (q & 7) * 4;
            const int rt = row >> 4, m = row & 15, quad = kq >> 3, j0 = kq & 7;
            const int off = rt * 1024 + (quad * 16 + m) * 16 + j0 * 2;
            const float4 v = av[i];
            ushort4 h, l;
            h.x = f2bf(v.x); l.x = f2bf(v.x - bf2f(h.x));
            h.y = f2bf(v.y); l.y = f2bf(v.y - bf2f(h.y));
            h.z = f2bf(v.z); l.z = f2bf(v.z - bf2f(h.z));
            h.w = f2bf(v.w); l.w = f2bf(v.w - bf2f(h.w));
            *(ushort4*)(Ahi + off) = h;
            *(ushort4*)(Alo + off) = l;
        }
        __syncthreads();

        bf16x8 ah[4], al[4], bh[CI], bl[CI];
#pragma unroll
        for (int i = 0; i < 4; ++i) {
            ah[i] = *(const bf16x8*)(Ahi + i * 1024 + lane * 16);
            al[i] = *(const bf16x8*)(Alo + i * 1024 + lane * 16);
        }
#pragma unroll
        for (int j = 0; j < CI; ++j) {
            bh[j] = *(const bf16x8*)(Bhi + (w * CI + j) * 1024 + lane * 16);
            bl[j] = *(const bf16x8*)(Blo + (w * CI + j) * 1024 + lane * 16);
        }
#pragma unroll
        for (int i = 0; i < 4; ++i)
#pragma unroll
            for (int j = 0; j < CI; ++j) {
                acc[i][j] = __builtin_amdgcn_mfma_f32_16x16x32_bf16(ah[i], bh[j], acc[i][j], 0, 0, 0);
                acc[i][j] = __builtin_amdgcn_mfma_f32_16x16x32_bf16(ah[i], bl[j], acc[i][j], 0, 0, 0);
                acc[i][j] = __builtin_amdgcn_mfma_f32_16x16x32_bf16(al[i], bh[j], acc[i][j], 0, 0, 0);
            }
        __syncthreads();
    }

    const int quad = lane >> 4;
    const int cl = lane & 15;
#pragma unroll
    for (int i = 0; i < 4; ++i) {
#pragma unroll
        for (int j = 0; j < CI; ++j) {
            const int colg = (w * CI + j) * 16 + cl;
            float bv = 0.f;
            if constexpr (BIAS_RELU) bv = bias[colg];
#pragma unroll
            for (int r = 0; r < 4; ++r) {
                const int rowg = r0 + i * 16 + quad * 4 + r;
                if (rowg < NNODES) {
                    float v = acc[i][j][r] + bv;
                    if constexpr (BIAS_RELU) v = fmaxf(v, 0.f);
                    C[(size_t)rowg * M + colg] = v;
                    if constexpr (WRITE_BF) Cbf[(size_t)rowg * M + colg] = f2bf(dinv[rowg] * v);
                }
            }
        }
    }
}

// ---------------- fp32 register-tiled GEMM ----------------

template <int BM, int BN, int BK, int TM, int TN, bool HAS_BIAS, bool RELU, bool WRITE_BF>
__global__ __launch_bounds__(256) void gemm_kernel(const float* __restrict__ A,
                                                   const float* __restrict__ W,
                                                   const float* __restrict__ bias,
                                                   float* __restrict__ C,
                                                   unsigned short* __restrict__ Cbf,
                                                   const float* __restrict__ dinv,
                                                   int Nrows, int K, int M) {
    constexpr int TX = BN / TN;
    constexpr int TY = BM / TM;
    static_assert(TX * TY == 256, "thread grid must be 256");
    constexpr int A_LOADS = (BM * BK) / (256 * 4);
    constexpr int W_LOADS = (BN * BK) / (256 * 4);
    static_assert(A_LOADS >= 1 && W_LOADS >= 1, "tile too small");

    const int tid = threadIdx.x;
    const int tx = tid % TX;
    const int ty = tid / TX;
    const int r0 = blockIdx.x * BM;
    const int c0 = blockIdx.y * BN;

    __shared__ float As[BK][BM + 4];
    __shared__ float Ws[BK][BN];

    float acc[TM][TN] = {};

    for (int k0 = 0; k0 < K; k0 += BK) {
#pragma unroll
        for (int l = 0; l < A_LOADS; ++l) {
            const int idx = tid + l * 256;
            const int row = idx / (BK / 4);
            const int kq = idx % (BK / 4);
            float4 v = make_float4(0.f, 0.f, 0.f, 0.f);
            const int gr = r0 + row;
            if (gr < Nrows) v = *(const float4*)(A + (size_t)gr * K + k0 + kq * 4);
            As[kq * 4 + 0][row] = v.x;
            As[kq * 4 + 1][row] = v.y;
            As[kq * 4 + 2][row] = v.z;
            As[kq * 4 + 3][row] = v.w;
        }
#pragma unroll
        for (int l = 0; l < W_LOADS; ++l) {
            const int idx = tid + l * 256;
            const int kk = idx / (BN / 4);
            const int cq = idx % (BN / 4);
            const int gc = c0 + cq * 4;
            float4 v;
            const float* wrow = W + (size_t)(k0 + kk) * M;
            if (gc + 3 < M) {
                v = *(const float4*)(wrow + gc);
            } else {
                v.x = (gc + 0 < M) ? wrow[gc + 0] : 0.f;
                v.y = (gc + 1 < M) ? wrow[gc + 1] : 0.f;
                v.z = (gc + 2 < M) ? wrow[gc + 2] : 0.f;
                v.w = (gc + 3 < M) ? wrow[gc + 3] : 0.f;
            }
            *(float4*)&Ws[kk][cq * 4] = v;
        }
        __syncthreads();

#pragma unroll
        for (int kk = 0; kk < BK; ++kk) {
            float a[TM], b[TN];
#pragma unroll
            for (int i = 0; i < TM; ++i) a[i] = As[kk][ty * TM + i];
#pragma unroll
            for (int j = 0; j < TN; ++j) b[j] = Ws[kk][tx * TN + j];
#pragma unroll
            for (int i = 0; i < TM; ++i)
#pragma unroll
                for (int j = 0; j < TN; ++j) acc[i][j] += a[i] * b[j];
        }
        __syncthreads();
    }

#pragma unroll
    for (int i = 0; i < TM; ++i) {
        const int gr = r0 + ty * TM + i;
        if (gr >= Nrows) continue;
        const float dvr = WRITE_BF ? dinv[gr] : 0.f;
#pragma unroll
        for (int j = 0; j < TN; ++j) {
            const int gc = c0 + tx * TN + j;
            if (gc >= M) continue;
            float v = acc[i][j];
            if constexpr (HAS_BIAS) v += bias[gc];
            if constexpr (RELU) v = fmaxf(v, 0.0f);
            C[(size_t)gr * M + gc] = v;
            if constexpr (WRITE_BF) Cbf[(size_t)gr * M + gc] = f2bf(dvr * v);
        }
    }
}

// ---------------- launch ----------------

extern "C" void kernel_launch(void* const* d_in, const int* in_sizes, int n_in,
                              void* d_out, int out_size, void* d_ws, size_t ws_size,
                              hipStream_t stream) {
    const float* x  = (const float*)d_in[0];
    const int* ei   = (const int*)d_in[1];
    const float* W1 = (const float*)d_in[2];
    const float* b1 = (const float*)d_in[3];
    const float* W2 = (const float*)d_in[4];
    const float* b2 = (const float*)d_in[5];
    const float* W3 = (const float*)d_in[6];
    const float* b3 = (const float*)d_in[7];
    const float* W4 = (const float*)d_in[8];
    const float* b4 = (const float*)d_in[9];
    float* out = (float*)d_out;
    const int* esrc = ei;
    const int* edst = ei + NEDGES;

    char* w = (char*)d_ws;
    auto alloc = [&](size_t bytes) -> void* {
        void* p = (void*)w;
        w += (bytes + 255) & ~(size_t)255;
        return p;
    };
    int* rp     = (int*)alloc((size_t)(NNODES + 1) * 4);
    unsigned short* col = (unsigned short*)alloc((size_t)NEDGES * 2);
    float* dinv = (float*)alloc((size_t)NNODES * 4);
    int* bhist  = (int*)alloc((size_t)NB * 4);
    int* bofs   = (int*)alloc((size_t)(NB + 1) * 4);
    int* gcur   = (int*)alloc((size_t)NB * 4);
    unsigned* gpk = (unsigned*)alloc((size_t)NEDGES * 4);
    unsigned short* W1hi = (unsigned short*)alloc((size_t)128 * 256 * 2);
    unsigned short* W1lo = (unsigned short*)alloc((size_t)128 * 256 * 2);
    unsigned short* W2hi = (unsigned short*)alloc((size_t)256 * 128 * 2);
    unsigned short* W2lo = (unsigned short*)alloc((size_t)256 * 128 * 2);
    float* B0   = (float*)alloc((size_t)NNODES * 256 * 4);
    float* B1   = (float*)alloc((size_t)NNODES * 128 * 4);
    float* B2   = (float*)alloc((size_t)NNODES * 128 * 4);
    unsigned short* xbf  = (unsigned short*)alloc((size_t)NNODES * 128 * 2);
    unsigned short* B1bf = (unsigned short*)alloc((size_t)NNODES * 128 * 2);
    unsigned short* B0bf = (unsigned short*)alloc((size_t)NNODES * 64 * 2);   // premult t3 mirror
    unsigned short* B3bf = (unsigned short*)alloc((size_t)NNODES * 64 * 2);   // premult h3 mirror

    // prep: repack W1+W2 + zero bhist (one dispatch)
    prep_kernel<<<(128 * 256 + 256 * 128) / 256, 256, 0, stream>>>(
        W1, W2, W1hi, W1lo, W2hi, W2lo, bhist);

    // bucketed CSR build (4 dispatches) — produces rp, col16, dinv, xbf
    bucket_count_kernel<<<SCAT_NBLK, 256, 0, stream>>>(edst, bhist);
    bucket_scan_kernel<<<1, 256, 0, stream>>>(bhist, bofs, gcur, rp + NNODES);
    bucket_scatter_kernel<<<SCAT_NBLK, 256, 0, stream>>>(esrc, edst, gcur, gpk);
    csr_fill_kernel<<<NB, 256, 0, stream>>>(gpk, bofs, rp, dinv, col, x, xbf);

    const int aggGrid = (NNODES + 3) / 4;
    const int rowBlks64 = (NNODES + 63) / 64;   // 782

    // Layer 1: aggregate first (dim 128), then MFMA GEMM 128->256 (+bias+relu), single pass
    agg128_kernel<false, false><<<aggGrid, 256, 0, stream>>>(x, xbf, B2, rp, col, dinv, nullptr);
    mfma_gemm_kernel<128, 256, true, false>
        <<<rowBlks64, 256, 0, stream>>>(B2, W1hi, W1lo, b1, B0, nullptr, nullptr);

    // Layer 2: MFMA GEMM 256->128 (emit premult bf16 mirror), then aggregate (+bias+relu)
    mfma_gemm_kernel<256, 128, false, true>
        <<<rowBlks64, 256, 0, stream>>>(B0, W2hi, W2lo, nullptr, B1, B1bf, dinv);
    agg128_kernel<true, true><<<aggGrid, 256, 0, stream>>>(B1, B1bf, B2, rp, col, dinv, b2);

    // Layer 3: fp32 GEMM 128->64 (emit premult t3 mirror), aggregate (+bias+relu, emit premult h3 mirror)
    gemm_kernel<64, 64, 16, 4, 4, false, false, true>
        <<<dim3(rowBlks64, 1), 256, 0, stream>>>(B2, W3, nullptr, B0, B0bf, dinv, NNODES, 128, 64);
    agg64_kernel<true, true, true><<<aggGrid, 256, 0, stream>>>(B0, B0bf, B1, B3bf, rp, col, dinv, b3);

    // Layer 4 (aggregate-first via linearity): pure agg64 on h3, then GEMM 64->40 (+bias) -> out
    agg64_kernel<false, false, false><<<aggGrid, 256, 0, stream>>>(B1, B3bf, B2, nullptr, rp, col, dinv, nullptr);
    gemm_kernel<64, 64, 16, 4, 4, true, false, false>
        <<<dim3(rowBlks64, 1), 256, 0, stream>>>(B2, W4, b4, out, nullptr, nullptr, NNODES, 64, 40);
}

// Round 7
// 328.070 us; speedup vs baseline: 1.5671x; 1.0534x over previous
//
#include <hip/hip_runtime.h>
#include <stdint.h>

#define NNODES 50000
#define NEDGES 800000
#define NB ((NNODES + 255) / 256)          // 196 dst-buckets (dst>>8); nodes align to buckets
#define EPB 4096                           // edges per scatter block
#define SCAT_NBLK ((NEDGES + EPB - 1) / EPB)  // 196
#define AGG_BLOCKS 2048                    // resident grid: 8 blocks/CU, grid-stride over dsts

typedef __attribute__((ext_vector_type(8))) short bf16x8;
typedef __attribute__((ext_vector_type(4))) float f32x4;

__device__ inline unsigned short f2bf(float f) {
    unsigned u = __float_as_uint(f);
    return (unsigned short)((u + 0x7fffu + ((u >> 16) & 1u)) >> 16);
}
__device__ inline float bf2f(unsigned short h) {
    return __uint_as_float(((unsigned)h) << 16);
}

// ---------------- bucketed CSR build ----------------
// src < 65536 so an edge packs as (dst&255)<<16 | src in one uint32; col stored as ushort.

__global__ void zero_kernel(int* __restrict__ p, int n) {
    int i = blockIdx.x * blockDim.x + threadIdx.x;
    if (i < n) p[i] = 0;
}

__global__ __launch_bounds__(256) void bucket_count_kernel(const int* __restrict__ dst,
                                                           int* __restrict__ bhist) {
    __shared__ int h[NB];
    for (int b = threadIdx.x; b < NB; b += 256) h[b] = 0;
    __syncthreads();
    const int base = blockIdx.x * EPB;
#pragma unroll
    for (int i = 0; i < EPB / 256; ++i) {
        const int e = base + threadIdx.x + i * 256;
        if (e < NEDGES) atomicAdd(&h[dst[e] >> 8], 1);
    }
    __syncthreads();
    for (int b = threadIdx.x; b < NB; b += 256)
        if (h[b]) atomicAdd(&bhist[b], h[b]);
}

__global__ __launch_bounds__(256) void bucket_scan_kernel(const int* __restrict__ bhist,
                                                          int* __restrict__ bofs,
                                                          int* __restrict__ gcur,
                                                          int* __restrict__ rp_last) {
    __shared__ int s[256];
    const int t = threadIdx.x;
    s[t] = (t < NB) ? bhist[t] : 0;
    __syncthreads();
    for (int off = 1; off < 256; off <<= 1) {
        int v = (t >= off) ? s[t - off] : 0;
        __syncthreads();
        s[t] += v;
        __syncthreads();
    }
    if (t < NB) {
        const int excl = (t > 0) ? s[t - 1] : 0;
        bofs[t] = excl;
        gcur[t] = excl;
    }
    if (t == 255) { bofs[NB] = s[255]; rp_last[0] = s[255]; }
}

__global__ __launch_bounds__(256) void bucket_scatter_kernel(const int* __restrict__ src,
                                                             const int* __restrict__ dst,
                                                             int* __restrict__ gcur,
                                                             unsigned* __restrict__ gpk) {
    __shared__ int h[256];
    __shared__ int s[256];
    __shared__ int gof[256];
    __shared__ unsigned pr[EPB];
    __shared__ int ga[EPB];

    const int t = threadIdx.x;
    const int base = blockIdx.x * EPB;
    const int nval = min(EPB, NEDGES - base);

    h[t] = 0;
    __syncthreads();
#pragma unroll
    for (int i = 0; i < EPB / 256; ++i) {
        const int e = base + t + i * 256;
        if (e < NEDGES) atomicAdd(&h[dst[e] >> 8], 1);
    }
    __syncthreads();
    s[t] = h[t];
    __syncthreads();
    for (int off = 1; off < 256; off <<= 1) {
        int v = (t >= off) ? s[t - off] : 0;
        __syncthreads();
        s[t] += v;
        __syncthreads();
    }
    {
        const int c = h[t];
        if (t < NB && c > 0) gof[t] = atomicAdd(&gcur[t], c);
        const int lofs = s[t] - c;
        h[t] = lofs;
        s[t] = lofs;
    }
    __syncthreads();
#pragma unroll
    for (int i = 0; i < EPB / 256; ++i) {
        const int e = base + t + i * 256;
        if (e < NEDGES) {
            const int d = dst[e];
            const int b = d >> 8;
            const int slot = atomicAdd(&h[b], 1);
            pr[slot] = ((unsigned)(d & 255) << 16) | (unsigned)src[e];
            ga[slot] = gof[b] + (slot - s[b]);
        }
    }
    __syncthreads();
#pragma unroll
    for (int i = 0; i < EPB / 256; ++i) {
        const int slot = t + i * 256;
        if (slot < nval) gpk[ga[slot]] = pr[slot];
    }
}

// Pass 4: per-bucket degree hist + scan -> rp/dinv, col fill (16-bit col)
__global__ __launch_bounds__(256) void csr_fill_kernel(const unsigned* __restrict__ gpk,
                                                       const int* __restrict__ bofs,
                                                       int* __restrict__ rp,
                                                       float* __restrict__ dinv,
                                                       unsigned short* __restrict__ col) {
    __shared__ int c[256];
    __shared__ int s[256];
    __shared__ int cur[256];
    const int t = threadIdx.x;
    const int b = blockIdx.x;
    const int beg = bofs[b], end = bofs[b + 1];
    c[t] = 0;
    __syncthreads();
    for (int e = beg + t; e < end; e += 256) atomicAdd(&c[gpk[e] >> 16], 1);
    __syncthreads();
    s[t] = c[t];
    __syncthreads();
    for (int off = 1; off < 256; off <<= 1) {
        int v = (t >= off) ? s[t - off] : 0;
        __syncthreads();
        s[t] += v;
        __syncthreads();
    }
    const int excl = s[t] - c[t];
    cur[t] = excl;
    const int node = b * 256 + t;
    if (node < NNODES) {
        rp[node] = beg + excl;
        dinv[node] = rsqrtf((float)(c[t] + 1));   // +1 self loop
    }
    __syncthreads();
    for (int e = beg + t; e < end; e += 256) {
        const unsigned p = gpk[e];
        const int r = atomicAdd(&cur[p >> 16], 1);
        col[beg + r] = (unsigned short)(p & 0xffffu);
    }
}

// ---------------- x -> premultiplied bf16 mirror: xbf[i] = bf16(dinv[row]*x[i]) ----

__global__ __launch_bounds__(256) void cvt_kernel(const float* __restrict__ in,
                                                  const float* __restrict__ dinv,
                                                  unsigned short* __restrict__ out, int n4) {
    int i = blockIdx.x * 256 + threadIdx.x;
    if (i >= n4) return;
    const float dv = dinv[i >> 5];                 // 32 float4-groups per 128-row
    float4 v = *(const float4*)(in + (size_t)i * 4);
    ushort4 h;
    h.x = f2bf(dv * v.x); h.y = f2bf(dv * v.y); h.z = f2bf(dv * v.z); h.w = f2bf(dv * v.w);
    *(ushort4*)(out + (size_t)i * 4) = h;
}

// ---------------- gather aggregation (premultiplied mirrors) ----------------
// out[d] = dinv[d] * ( dinv[d]*in32[d] + sum_s mirror[s] ) [+bias][relu]
// F=128: wave per dst, GRID-STRIDE over dsts (resident grid, waves stay alive,
// next node's rp/col loads overlap previous node's gather drain).
// QUARTER-wave (16 lanes x 16B) per edge; 4-deep unroll -> 16 gathers in flight.

template <bool RELU, bool HAS_BIAS>
__global__ __launch_bounds__(256) void agg128_kernel(const float* __restrict__ in32,
                                                     const unsigned short* __restrict__ inbf,
                                                     float* __restrict__ out,
                                                     const int* __restrict__ rp,
                                                     const unsigned short* __restrict__ col,
                                                     const float* __restrict__ dinv,
                                                     const float* __restrict__ bias) {
    const int wave = threadIdx.x >> 6;
    const int lane = threadIdx.x & 63;
    const int quarter = lane >> 4;   // 0..3 : which edge of a group of 4
    const int fl = lane & 15;        // 16 lanes x 8 features = 128
    const int dstride = gridDim.x * 4;

    for (int d = blockIdx.x * 4 + wave; d < NNODES; d += dstride) {
        const float dv = dinv[d];

        float acc[8] = {0.f, 0.f, 0.f, 0.f, 0.f, 0.f, 0.f, 0.f};
        if (quarter == 0) {
            float4 s0 = *(const float4*)(in32 + (size_t)d * 128 + fl * 8);
            float4 s1 = *(const float4*)(in32 + (size_t)d * 128 + fl * 8 + 4);
            acc[0] = dv * s0.x; acc[1] = dv * s0.y; acc[2] = dv * s0.z; acc[3] = dv * s0.w;
            acc[4] = dv * s1.x; acc[5] = dv * s1.y; acc[6] = dv * s1.z; acc[7] = dv * s1.w;
        }

        int j = rp[d] + quarter;
        const int end = rp[d + 1];
        // 4-deep: 16 edges per wave per iteration
        for (; j + 12 < end; j += 16) {
            const int c0 = col[j], c1 = col[j + 4], c2 = col[j + 8], c3 = col[j + 12];
            bf16x8 a0 = *(const bf16x8*)(inbf + (size_t)c0 * 128 + fl * 8);
            bf16x8 a1 = *(const bf16x8*)(inbf + (size_t)c1 * 128 + fl * 8);
            bf16x8 a2 = *(const bf16x8*)(inbf + (size_t)c2 * 128 + fl * 8);
            bf16x8 a3 = *(const bf16x8*)(inbf + (size_t)c3 * 128 + fl * 8);
#pragma unroll
            for (int k = 0; k < 8; ++k)
                acc[k] += (bf2f((unsigned short)a0[k]) + bf2f((unsigned short)a1[k])) +
                          (bf2f((unsigned short)a2[k]) + bf2f((unsigned short)a3[k]));
        }
        // 2-deep tail
        for (; j + 4 < end; j += 8) {
            const int c0 = col[j], c1 = col[j + 4];
            bf16x8 a0 = *(const bf16x8*)(inbf + (size_t)c0 * 128 + fl * 8);
            bf16x8 a1 = *(const bf16x8*)(inbf + (size_t)c1 * 128 + fl * 8);
#pragma unroll
            for (int k = 0; k < 8; ++k)
                acc[k] += bf2f((unsigned short)a0[k]) + bf2f((unsigned short)a1[k]);
        }
        if (j < end) {
            const int c0 = col[j];
            bf16x8 a0 = *(const bf16x8*)(inbf + (size_t)c0 * 128 + fl * 8);
#pragma unroll
            for (int k = 0; k < 8; ++k) acc[k] += bf2f((unsigned short)a0[k]);
        }

#pragma unroll
        for (int v = 0; v < 8; ++v) {
            acc[v] += __shfl_down(acc[v], 32);
            acc[v] += __shfl_down(acc[v], 16);
        }

        if (quarter == 0) {
            float r[8];
#pragma unroll
            for (int v = 0; v < 8; ++v) {
                float t = dv * acc[v];
                if constexpr (HAS_BIAS) t += bias[fl * 8 + v];
                if constexpr (RELU) t = fmaxf(t, 0.0f);
                r[v] = t;
            }
            *(float4*)(out + (size_t)d * 128 + fl * 8)     = make_float4(r[0], r[1], r[2], r[3]);
            *(float4*)(out + (size_t)d * 128 + fl * 8 + 4) = make_float4(r[4], r[5], r[6], r[7]);
        }
    }
}

// F=64: wave per dst, GRID-STRIDE; EIGHTH-wave (8 lanes x 16B = one 128B line)
// per edge; 2-deep unroll -> 16 gathers in flight per wave.
// Optional premultiplied bf16 mirror of the OUTPUT (for a following aggregate-first layer).
template <bool RELU, bool HAS_BIAS, bool WRITE_BF>
__global__ __launch_bounds__(256) void agg64_kernel(const float* __restrict__ in32,
                                                    const unsigned short* __restrict__ inbf,
                                                    float* __restrict__ out,
                                                    unsigned short* __restrict__ outbf,
                                                    const int* __restrict__ rp,
                                                    const unsigned short* __restrict__ col,
                                                    const float* __restrict__ dinv,
                                                    const float* __restrict__ bias) {
    const int wave = threadIdx.x >> 6;
    const int lane = threadIdx.x & 63;
    const int eighth = lane >> 3;    // 0..7 : which edge of a group of 8
    const int fl = lane & 7;         // 8 lanes x 8 features = 64
    const int dstride = gridDim.x * 4;

    for (int d = blockIdx.x * 4 + wave; d < NNODES; d += dstride) {
        const float dv = dinv[d];

        float acc[8] = {0.f, 0.f, 0.f, 0.f, 0.f, 0.f, 0.f, 0.f};
        if (eighth == 0) {
            float4 s0 = *(const float4*)(in32 + (size_t)d * 64 + fl * 8);
            float4 s1 = *(const float4*)(in32 + (size_t)d * 64 + fl * 8 + 4);
            acc[0] = dv * s0.x; acc[1] = dv * s0.y; acc[2] = dv * s0.z; acc[3] = dv * s0.w;
            acc[4] = dv * s1.x; acc[5] = dv * s1.y; acc[6] = dv * s1.z; acc[7] = dv * s1.w;
        }

        int j = rp[d] + eighth;
        const int end = rp[d + 1];
        for (; j + 8 < end; j += 16) {
            const int c0 = col[j], c1 = col[j + 8];
            bf16x8 a0 = *(const bf16x8*)(inbf + (size_t)c0 * 64 + fl * 8);
            bf16x8 a1 = *(const bf16x8*)(inbf + (size_t)c1 * 64 + fl * 8);
#pragma unroll
            for (int k = 0; k < 8; ++k)
                acc[k] += bf2f((unsigned short)a0[k]) + bf2f((unsigned short)a1[k]);
        }
        if (j < end) {
            const int c0 = col[j];
            bf16x8 a0 = *(const bf16x8*)(inbf + (size_t)c0 * 64 + fl * 8);
#pragma unroll
            for (int k = 0; k < 8; ++k) acc[k] += bf2f((unsigned short)a0[k]);
        }

#pragma unroll
        for (int v = 0; v < 8; ++v) {
            acc[v] += __shfl_down(acc[v], 32);
            acc[v] += __shfl_down(acc[v], 16);
            acc[v] += __shfl_down(acc[v], 8);
        }

        if (eighth == 0) {
            float r[8];
#pragma unroll
            for (int v = 0; v < 8; ++v) {
                float t = dv * acc[v];
                if constexpr (HAS_BIAS) t += bias[fl * 8 + v];
                if constexpr (RELU) t = fmaxf(t, 0.0f);
                r[v] = t;
            }
            *(float4*)(out + (size_t)d * 64 + fl * 8)     = make_float4(r[0], r[1], r[2], r[3]);
            *(float4*)(out + (size_t)d * 64 + fl * 8 + 4) = make_float4(r[4], r[5], r[6], r[7]);
            if constexpr (WRITE_BF) {
                ushort4 h0, h1;
                h0.x = f2bf(dv * r[0]); h0.y = f2bf(dv * r[1]);
                h0.z = f2bf(dv * r[2]); h0.w = f2bf(dv * r[3]);
                h1.x = f2bf(dv * r[4]); h1.y = f2bf(dv * r[5]);
                h1.z = f2bf(dv * r[6]); h1.w = f2bf(dv * r[7]);
                *(ushort4*)(outbf + (size_t)d * 64 + fl * 8)     = h0;
                *(ushort4*)(outbf + (size_t)d * 64 + fl * 8 + 4) = h1;
            }
        }
    }
}

// ---------------- weight repack: W[K][M] fp32 -> split-bf16 fragment order ----

template <int K, int M>
__global__ __launch_bounds__(256) void repack_kernel(const float* __restrict__ W,
                                                     unsigned short* __restrict__ hi,
                                                     unsigned short* __restrict__ lo) {
    int i = blockIdx.x * 256 + threadIdx.x;
    if (i >= K * M) return;
    const int k = i / M, n = i % M;
    constexpr int KS = K / 32;
    const int cb = n >> 7;
    const int ct = (n >> 4) & 7;
    const int ln = ((k >> 3) & 3) * 16 + (n & 15);
    const int j  = k & 7;
    const int ks = k >> 5;
    const size_t o = ((((size_t)cb * KS + ks) * 8 + ct) * 64 + ln) * 8 + j;
    const float f = W[i];
    const unsigned short h = f2bf(f);
    hi[o] = h;
    lo[o] = f2bf(f - bf2f(h));
}

// ---------------- split-bf16 MFMA GEMM (round-1 proven form) ----------------
// BM=64: 4 waves in 1x4, each 64x32. bf mirror premultiplied by dinv[row].

template <int K, int M, int BM, bool BIAS_RELU, bool WRITE_BF>
__global__ __launch_bounds__(256) void mfma_gemm_kernel(const float* __restrict__ A,
                                                        const unsigned short* __restrict__ Whi,
                                                        const unsigned short* __restrict__ Wlo,
                                                        const float* __restrict__ bias,
                                                        float* __restrict__ C,
                                                        unsigned short* __restrict__ Cbf,
                                                        const float* __restrict__ dinv) {
    constexpr int KS = K / 32;
    constexpr int ASZ = BM * 64;
    constexpr int CI = (BM == 128) ? 4 : 2;
    __shared__ char lds[2 * ASZ + 16384];
    char* Ahi = lds;
    char* Alo = lds + ASZ;
    char* Bhi = lds + 2 * ASZ;
    char* Blo = lds + 2 * ASZ + 8192;

    const int t = threadIdx.x;
    const int lane = t & 63;
    const int w = t >> 6;
    const int wr = (BM == 128) ? (w >> 1) : 0;
    const int wc = (BM == 128) ? (w & 1) : w;
    const int r0 = blockIdx.x * BM;
    const int n0 = blockIdx.y * 128;

    const unsigned short* bhg = Whi + (size_t)blockIdx.y * KS * 4096;
    const unsigned short* blg = Wlo + (size_t)blockIdx.y * KS * 4096;

    f32x4 acc[4][CI];
#pragma unroll
    for (int i = 0; i < 4; ++i)
#pragma unroll
        for (int j = 0; j < CI; ++j) acc[i][j] = (f32x4){0.f, 0.f, 0.f, 0.f};

    for (int ks = 0; ks < KS; ++ks) {
        const int k0 = ks * 32;

        {
            const char* gh = (const char*)(bhg + (size_t)ks * 4096);
            const char* gl = (const char*)(blg + (size_t)ks * 4096);
#pragma unroll
            for (int c = 0; c < 2; ++c) {
                const int ct = w * 2 + c;
                __builtin_amdgcn_global_load_lds(
                    (const __attribute__((address_space(1))) void*)(gh + ct * 1024 + lane * 16),
                    (__attribute__((address_space(3))) void*)(Bhi + ct * 1024), 16, 0, 0);
                __builtin_amdgcn_global_load_lds(
                    (const __attribute__((address_space(1))) void*)(gl + ct * 1024 + lane * 16),
                    (__attribute__((address_space(3))) void*)(Blo + ct * 1024), 16, 0, 0);
            }
        }

        float4 av[BM / 32];
#pragma unroll
        for (int i = 0; i < BM / 32; ++i) {
            const int q = t + i * 256;
            const int row = q >> 3;
            const int kq = (q & 7) * 4;
            const int gr = r0 + row;
            float4 v = make_float4(0.f, 0.f, 0.f, 0.f);
            if (gr < NNODES) v = *(const float4*)(A + (size_t)gr * K + k0 + kq);
            av[i] = v;
        }
#pragma unroll
        for (int i = 0; i < BM / 32; ++i) {
            const int q = t + i * 256;
            const int row = q >> 3;
            const int kq = (q & 7) * 4;
            const int rt = row >> 4, m = row & 15, quad = kq >> 3, j0 = kq & 7;
            const int off = rt * 1024 + (quad * 16 + m) * 16 + j0 * 2;
            const float4 v = av[i];
            ushort4 h, l;
            h.x = f2bf(v.x); l.x = f2bf(v.x - bf2f(h.x));
            h.y = f2bf(v.y); l.y = f2bf(v.y - bf2f(h.y));
            h.z = f2bf(v.z); l.z = f2bf(v.z - bf2f(h.z));
            h.w = f2bf(v.w); l.w = f2bf(v.w - bf2f(h.w));
            *(ushort4*)(Ahi + off) = h;
            *(ushort4*)(Alo + off) = l;
        }
        __syncthreads();

        bf16x8 ah[4], al[4], bh[CI], bl[CI];
#pragma unroll
        for (int i = 0; i < 4; ++i) {
            ah[i] = *(const bf16x8*)(Ahi + (wr * 4 + i) * 1024 + lane * 16);
            al[i] = *(const bf16x8*)(Alo + (wr * 4 + i) * 1024 + lane * 16);
        }
#pragma unroll
        for (int j = 0; j < CI; ++j) {
            bh[j] = *(const bf16x8*)(Bhi + (wc * CI + j) * 1024 + lane * 16);
            bl[j] = *(const bf16x8*)(Blo + (wc * CI + j) * 1024 + lane * 16);
        }
#pragma unroll
        for (int i = 0; i < 4; ++i)
#pragma unroll
            for (int j = 0; j < CI; ++j) {
                acc[i][j] = __builtin_amdgcn_mfma_f32_16x16x32_bf16(ah[i], bh[j], acc[i][j], 0, 0, 0);
                acc[i][j] = __builtin_amdgcn_mfma_f32_16x16x32_bf16(ah[i], bl[j], acc[i][j], 0, 0, 0);
                acc[i][j] = __builtin_amdgcn_mfma_f32_16x16x32_bf16(al[i], bh[j], acc[i][j], 0, 0, 0);
            }
        __syncthreads();
    }

    const int quad = lane >> 4;
    const int cl = lane & 15;
#pragma unroll
    for (int i = 0; i < 4; ++i) {
#pragma unroll
        for (int j = 0; j < CI; ++j) {
            const int colg = n0 + wc * (CI * 16) + j * 16 + cl;
            float bv = 0.f;
            if constexpr (BIAS_RELU) bv = bias[colg];
#pragma unroll
            for (int r = 0; r < 4; ++r) {
                const int rowg = r0 + wr * 64 + i * 16 + quad * 4 + r;
                if (rowg < NNODES) {
                    float v = acc[i][j][r] + bv;
                    if constexpr (BIAS_RELU) v = fmaxf(v, 0.f);
                    C[(size_t)rowg * M + colg] = v;
                    if constexpr (WRITE_BF) Cbf[(size_t)rowg * M + colg] = f2bf(dinv[rowg] * v);
                }
            }
        }
    }
}

// ---------------- fp32 register-tiled GEMM ----------------

template <int BM, int BN, int BK, int TM, int TN, bool HAS_BIAS, bool RELU, bool WRITE_BF>
__global__ __launch_bounds__(256) void gemm_kernel(const float* __restrict__ A,
                                                   const float* __restrict__ W,
                                                   const float* __restrict__ bias,
                                                   float* __restrict__ C,
                                                   unsigned short* __restrict__ Cbf,
                                                   const float* __restrict__ dinv,
                                                   int Nrows, int K, int M) {
    constexpr int TX = BN / TN;
    constexpr int TY = BM / TM;
    static_assert(TX * TY == 256, "thread grid must be 256");
    constexpr int A_LOADS = (BM * BK) / (256 * 4);
    constexpr int W_LOADS = (BN * BK) / (256 * 4);
    static_assert(A_LOADS >= 1 && W_LOADS >= 1, "tile too small");

    const int tid = threadIdx.x;
    const int tx = tid % TX;
    const int ty = tid / TX;
    const int r0 = blockIdx.x * BM;
    const int c0 = blockIdx.y * BN;

    __shared__ float As[BK][BM + 4];
    __shared__ float Ws[BK][BN];

    float acc[TM][TN] = {};

    for (int k0 = 0; k0 < K; k0 += BK) {
#pragma unroll
        for (int l = 0; l < A_LOADS; ++l) {
            const int idx = tid + l * 256;
            const int row = idx / (BK / 4);
            const int kq = idx % (BK / 4);
            float4 v = make_float4(0.f, 0.f, 0.f, 0.f);
            const int gr = r0 + row;
            if (gr < Nrows) v = *(const float4*)(A + (size_t)gr * K + k0 + kq * 4);
            As[kq * 4 + 0][row] = v.x;
            As[kq * 4 + 1][row] = v.y;
            As[kq * 4 + 2][row] = v.z;
            As[kq * 4 + 3][row] = v.w;
        }
#pragma unroll
        for (int l = 0; l < W_LOADS; ++l) {
            const int idx = tid + l * 256;
            const int kk = idx / (BN / 4);
            const int cq = idx % (BN / 4);
            const int gc = c0 + cq * 4;
            float4 v;
            const float* wrow = W + (size_t)(k0 + kk) * M;
            if (gc + 3 < M) {
                v = *(const float4*)(wrow + gc);
            } else {
                v.x = (gc + 0 < M) ? wrow[gc + 0] : 0.f;
                v.y = (gc + 1 < M) ? wrow[gc + 1] : 0.f;
                v.z = (gc + 2 < M) ? wrow[gc + 2] : 0.f;
                v.w = (gc + 3 < M) ? wrow[gc + 3] : 0.f;
            }
            *(float4*)&Ws[kk][cq * 4] = v;
        }
        __syncthreads();

#pragma unroll
        for (int kk = 0; kk < BK; ++kk) {
            float a[TM], b[TN];
#pragma unroll
            for (int i = 0; i < TM; ++i) a[i] = As[kk][ty * TM + i];
#pragma unroll
            for (int j = 0; j < TN; ++j) b[j] = Ws[kk][tx * TN + j];
#pragma unroll
            for (int i = 0; i < TM; ++i)
#pragma unroll
                for (int j = 0; j < TN; ++j) acc[i][j] += a[i] * b[j];
        }
        __syncthreads();
    }

#pragma unroll
    for (int i = 0; i < TM; ++i) {
        const int gr = r0 + ty * TM + i;
        if (gr >= Nrows) continue;
        const float dvr = WRITE_BF ? dinv[gr] : 0.f;
#pragma unroll
        for (int j = 0; j < TN; ++j) {
            const int gc = c0 + tx * TN + j;
            if (gc >= M) continue;
            float v = acc[i][j];
            if constexpr (HAS_BIAS) v += bias[gc];
            if constexpr (RELU) v = fmaxf(v, 0.0f);
            C[(size_t)gr * M + gc] = v;
            if constexpr (WRITE_BF) Cbf[(size_t)gr * M + gc] = f2bf(dvr * v);
        }
    }
}

// ---------------- launch ----------------

extern "C" void kernel_launch(void* const* d_in, const int* in_sizes, int n_in,
                              void* d_out, int out_size, void* d_ws, size_t ws_size,
                              hipStream_t stream) {
    const float* x  = (const float*)d_in[0];
    const int* ei   = (const int*)d_in[1];
    const float* W1 = (const float*)d_in[2];
    const float* b1 = (const float*)d_in[3];
    const float* W2 = (const float*)d_in[4];
    const float* b2 = (const float*)d_in[5];
    const float* W3 = (const float*)d_in[6];
    const float* b3 = (const float*)d_in[7];
    const float* W4 = (const float*)d_in[8];
    const float* b4 = (const float*)d_in[9];
    float* out = (float*)d_out;
    const int* esrc = ei;
    const int* edst = ei + NEDGES;

    char* w = (char*)d_ws;
    auto alloc = [&](size_t bytes) -> void* {
        void* p = (void*)w;
        w += (bytes + 255) & ~(size_t)255;
        return p;
    };
    int* rp     = (int*)alloc((size_t)(NNODES + 1) * 4);
    unsigned short* col = (unsigned short*)alloc((size_t)NEDGES * 2);
    float* dinv = (float*)alloc((size_t)NNODES * 4);
    int* bhist  = (int*)alloc((size_t)NB * 4);
    int* bofs   = (int*)alloc((size_t)(NB + 1) * 4);
    int* gcur   = (int*)alloc((size_t)NB * 4);
    unsigned* gpk = (unsigned*)alloc((size_t)NEDGES * 4);
    unsigned short* W1hi = (unsigned short*)alloc((size_t)128 * 256 * 2);
    unsigned short* W1lo = (unsigned short*)alloc((size_t)128 * 256 * 2);
    unsigned short* W2hi = (unsigned short*)alloc((size_t)256 * 128 * 2);
    unsigned short* W2lo = (unsigned short*)alloc((size_t)256 * 128 * 2);
    float* B0   = (float*)alloc((size_t)NNODES * 256 * 4);
    float* B1   = (float*)alloc((size_t)NNODES * 128 * 4);
    float* B2   = (float*)alloc((size_t)NNODES * 128 * 4);
    unsigned short* xbf  = (unsigned short*)alloc((size_t)NNODES * 128 * 2);
    unsigned short* B1bf = (unsigned short*)alloc((size_t)NNODES * 128 * 2);
    unsigned short* B0bf = (unsigned short*)alloc((size_t)NNODES * 64 * 2);   // premult t3 mirror
    unsigned short* B3bf = (unsigned short*)alloc((size_t)NNODES * 64 * 2);   // premult h3 mirror

    // weight repack (tiny, independent)
    repack_kernel<128, 256><<<(128 * 256 + 255) / 256, 256, 0, stream>>>(W1, W1hi, W1lo);
    repack_kernel<256, 128><<<(256 * 128 + 255) / 256, 256, 0, stream>>>(W2, W2hi, W2lo);

    // bucketed CSR build (5 dispatches) — produces rp, col16, dinv
    zero_kernel<<<1, 256, 0, stream>>>(bhist, NB);
    bucket_count_kernel<<<SCAT_NBLK, 256, 0, stream>>>(edst, bhist);
    bucket_scan_kernel<<<1, 256, 0, stream>>>(bhist, bofs, gcur, rp + NNODES);
    bucket_scatter_kernel<<<SCAT_NBLK, 256, 0, stream>>>(esrc, edst, gcur, gpk);
    csr_fill_kernel<<<NB, 256, 0, stream>>>(gpk, bofs, rp, dinv, col);

    // x mirror premultiplied by dinv (needs dinv)
    cvt_kernel<<<(NNODES * 128 / 4 + 255) / 256, 256, 0, stream>>>(x, dinv, xbf, NNODES * 128 / 4);

    const int rowBlks64 = (NNODES + 63) / 64;   // 782

    // Layer 1: aggregate first (dim 128), then MFMA GEMM 128->256 (+bias+relu)
    agg128_kernel<false, false><<<AGG_BLOCKS, 256, 0, stream>>>(x, xbf, B2, rp, col, dinv, nullptr);
    mfma_gemm_kernel<128, 256, 64, true, false>
        <<<dim3(rowBlks64, 2), 256, 0, stream>>>(B2, W1hi, W1lo, b1, B0, nullptr, nullptr);

    // Layer 2: MFMA GEMM 256->128 (emit premult bf16 mirror), then aggregate (+bias+relu)
    mfma_gemm_kernel<256, 128, 64, false, true>
        <<<dim3(rowBlks64, 1), 256, 0, stream>>>(B0, W2hi, W2lo, nullptr, B1, B1bf, dinv);
    agg128_kernel<true, true><<<AGG_BLOCKS, 256, 0, stream>>>(B1, B1bf, B2, rp, col, dinv, b2);

    // Layer 3: fp32 GEMM 128->64 (emit premult t3 mirror), aggregate (+bias+relu, emit premult h3 mirror)
    gemm_kernel<64, 64, 16, 4, 4, false, false, true>
        <<<dim3(rowBlks64, 1), 256, 0, stream>>>(B2, W3, nullptr, B0, B0bf, dinv, NNODES, 128, 64);
    agg64_kernel<true, true, true><<<AGG_BLOCKS, 256, 0, stream>>>(B0, B0bf, B1, B3bf, rp, col, dinv, b3);

    // Layer 4 (aggregate-first via linearity): pure agg64 on h3, then GEMM 64->40 (+bias) -> out
    agg64_kernel<false, false, false><<<AGG_BLOCKS, 256, 0, stream>>>(B1, B3bf, B2, nullptr, rp, col, dinv, nullptr);
    gemm_kernel<64, 64, 16, 4, 4, true, false, false>
        <<<dim3(rowBlks64, 1), 256, 0, stream>>>(B2, W4, b4, out, nullptr, nullptr, NNODES, 64, 40);
}

// Round 8
// 320.137 us; speedup vs baseline: 1.6059x; 1.0248x over previous
//
#include <hip/hip_runtime.h>
#include <stdint.h>

#define NNODES 50000
#define NEDGES 800000
#define NB ((NNODES + 255) / 256)          // 196 dst-buckets (dst>>8); nodes align to buckets
#define EPB 4096                           // edges per scatter block
#define SCAT_NBLK ((NEDGES + EPB - 1) / EPB)  // 196
#define BUCKCAP 8192                       // padded gpk capacity per bucket (mean 4096, sigma 64)
#define AGG_BLOCKS 2048                    // resident grid: 8 blocks/CU, grid-stride over dsts

typedef __attribute__((ext_vector_type(8))) short bf16x8;
typedef __attribute__((ext_vector_type(4))) float f32x4;

__device__ inline unsigned short f2bf(float f) {
    unsigned u = __float_as_uint(f);
    return (unsigned short)((u + 0x7fffu + ((u >> 16) & 1u)) >> 16);
}
__device__ inline float bf2f(unsigned short h) {
    return __uint_as_float(((unsigned)h) << 16);
}

// ---------------- bucketed CSR build (direct-scatter, 2 dispatches) ----------------
// src < 65536 so an edge packs as (dst&255)<<16 | src in one uint32; col stored as ushort.
// gcur starts at 0; scatter blocks reserve per-bucket ranges via atomicAdd and
// write into padded gpk[bucket*BUCKCAP + ...]. Within-bucket order is already
// non-deterministic in the proven pipeline (racing atomics), so this is
// order-equivalent. csr_fill2 re-derives dense offsets with an in-block scan.

__global__ __launch_bounds__(256) void scatter_direct_kernel(const int* __restrict__ src,
                                                             const int* __restrict__ dst,
                                                             int* __restrict__ gcur,
                                                             unsigned* __restrict__ gpk) {
    __shared__ int h[256];
    __shared__ int s[256];
    __shared__ int gof[256];
    __shared__ unsigned pr[EPB];
    __shared__ int ga[EPB];

    const int t = threadIdx.x;
    const int base = blockIdx.x * EPB;
    const int nval = min(EPB, NEDGES - base);

    h[t] = 0;
    __syncthreads();
#pragma unroll
    for (int i = 0; i < EPB / 256; ++i) {
        const int e = base + t + i * 256;
        if (e < NEDGES) atomicAdd(&h[dst[e] >> 8], 1);
    }
    __syncthreads();
    s[t] = h[t];
    __syncthreads();
    for (int off = 1; off < 256; off <<= 1) {
        int v = (t >= off) ? s[t - off] : 0;
        __syncthreads();
        s[t] += v;
        __syncthreads();
    }
    {
        const int c = h[t];
        if (t < NB && c > 0) gof[t] = atomicAdd(&gcur[t], c);
        const int lofs = s[t] - c;
        h[t] = lofs;
        s[t] = lofs;
    }
    __syncthreads();
#pragma unroll
    for (int i = 0; i < EPB / 256; ++i) {
        const int e = base + t + i * 256;
        if (e < NEDGES) {
            const int d = dst[e];
            const int b = d >> 8;
            const int slot = atomicAdd(&h[b], 1);
            pr[slot] = ((unsigned)(d & 255) << 16) | (unsigned)src[e];
            ga[slot] = b * BUCKCAP + gof[b] + (slot - s[b]);
        }
    }
    __syncthreads();
#pragma unroll
    for (int i = 0; i < EPB / 256; ++i) {
        const int slot = t + i * 256;
        if (slot < nval) gpk[ga[slot]] = pr[slot];
    }
}

// Per-bucket: redundant in-block scan of bucket counts -> dense beg; degree
// hist + scan -> rp/dinv; col fill (16-bit col) from padded gpk.
__global__ __launch_bounds__(256) void csr_fill2_kernel(const unsigned* __restrict__ gpk,
                                                        const int* __restrict__ gcur,
                                                        int* __restrict__ rp,
                                                        float* __restrict__ dinv,
                                                        unsigned short* __restrict__ col) {
    __shared__ int c[256];
    __shared__ int s[256];
    __shared__ int cur[256];
    const int t = threadIdx.x;
    const int b = blockIdx.x;

    // dense bucket offsets (redundant 196-entry scan per block)
    s[t] = (t < NB) ? gcur[t] : 0;
    __syncthreads();
    for (int off = 1; off < 256; off <<= 1) {
        int v = (t >= off) ? s[t - off] : 0;
        __syncthreads();
        s[t] += v;
        __syncthreads();
    }
    const int beg = (b > 0) ? s[b - 1] : 0;
    const int cnt = s[b] - beg;
    if (b == 0 && t == 255) rp[NNODES] = s[255];
    __syncthreads();

    const unsigned* g = gpk + (size_t)b * BUCKCAP;
    c[t] = 0;
    __syncthreads();
    for (int e = t; e < cnt; e += 256) atomicAdd(&c[g[e] >> 16], 1);
    __syncthreads();
    s[t] = c[t];
    __syncthreads();
    for (int off = 1; off < 256; off <<= 1) {
        int v = (t >= off) ? s[t - off] : 0;
        __syncthreads();
        s[t] += v;
        __syncthreads();
    }
    const int excl = s[t] - c[t];
    cur[t] = excl;
    const int node = b * 256 + t;
    if (node < NNODES) {
        rp[node] = beg + excl;
        dinv[node] = rsqrtf((float)(c[t] + 1));   // +1 self loop
    }
    __syncthreads();
    for (int e = t; e < cnt; e += 256) {
        const unsigned p = g[e];
        const int r = atomicAdd(&cur[p >> 16], 1);
        col[beg + r] = (unsigned short)(p & 0xffffu);
    }
}

// ---------------- x -> premultiplied bf16 mirror: xbf[i] = bf16(dinv[row]*x[i]) ----

__global__ __launch_bounds__(256) void cvt_kernel(const float* __restrict__ in,
                                                  const float* __restrict__ dinv,
                                                  unsigned short* __restrict__ out, int n4) {
    int i = blockIdx.x * 256 + threadIdx.x;
    if (i >= n4) return;
    const float dv = dinv[i >> 5];                 // 32 float4-groups per 128-row
    float4 v = *(const float4*)(in + (size_t)i * 4);
    ushort4 h;
    h.x = f2bf(dv * v.x); h.y = f2bf(dv * v.y); h.z = f2bf(dv * v.z); h.w = f2bf(dv * v.w);
    *(ushort4*)(out + (size_t)i * 4) = h;
}

// ---------------- gather aggregation (premultiplied mirrors) ----------------
// out[d] = dinv[d] * ( dinv[d]*in32[d] + sum_s mirror[s] ) [+bias][relu]
// F=128: wave per dst, GRID-STRIDE over dsts (resident grid, waves stay alive,
// next node's rp/col loads overlap previous node's gather drain).
// QUARTER-wave (16 lanes x 16B) per edge; 4-deep unroll -> 16 gathers in flight.

template <bool RELU, bool HAS_BIAS>
__global__ __launch_bounds__(256) void agg128_kernel(const float* __restrict__ in32,
                                                     const unsigned short* __restrict__ inbf,
                                                     float* __restrict__ out,
                                                     const int* __restrict__ rp,
                                                     const unsigned short* __restrict__ col,
                                                     const float* __restrict__ dinv,
                                                     const float* __restrict__ bias) {
    const int wave = threadIdx.x >> 6;
    const int lane = threadIdx.x & 63;
    const int quarter = lane >> 4;   // 0..3 : which edge of a group of 4
    const int fl = lane & 15;        // 16 lanes x 8 features = 128
    const int dstride = gridDim.x * 4;

    for (int d = blockIdx.x * 4 + wave; d < NNODES; d += dstride) {
        const float dv = dinv[d];

        float acc[8] = {0.f, 0.f, 0.f, 0.f, 0.f, 0.f, 0.f, 0.f};
        if (quarter == 0) {
            float4 s0 = *(const float4*)(in32 + (size_t)d * 128 + fl * 8);
            float4 s1 = *(const float4*)(in32 + (size_t)d * 128 + fl * 8 + 4);
            acc[0] = dv * s0.x; acc[1] = dv * s0.y; acc[2] = dv * s0.z; acc[3] = dv * s0.w;
            acc[4] = dv * s1.x; acc[5] = dv * s1.y; acc[6] = dv * s1.z; acc[7] = dv * s1.w;
        }

        int j = rp[d] + quarter;
        const int end = rp[d + 1];
        // 4-deep: 16 edges per wave per iteration
        for (; j + 12 < end; j += 16) {
            const int c0 = col[j], c1 = col[j + 4], c2 = col[j + 8], c3 = col[j + 12];
            bf16x8 a0 = *(const bf16x8*)(inbf + (size_t)c0 * 128 + fl * 8);
            bf16x8 a1 = *(const bf16x8*)(inbf + (size_t)c1 * 128 + fl * 8);
            bf16x8 a2 = *(const bf16x8*)(inbf + (size_t)c2 * 128 + fl * 8);
            bf16x8 a3 = *(const bf16x8*)(inbf + (size_t)c3 * 128 + fl * 8);
#pragma unroll
            for (int k = 0; k < 8; ++k)
                acc[k] += (bf2f((unsigned short)a0[k]) + bf2f((unsigned short)a1[k])) +
                          (bf2f((unsigned short)a2[k]) + bf2f((unsigned short)a3[k]));
        }
        // 2-deep tail
        for (; j + 4 < end; j += 8) {
            const int c0 = col[j], c1 = col[j + 4];
            bf16x8 a0 = *(const bf16x8*)(inbf + (size_t)c0 * 128 + fl * 8);
            bf16x8 a1 = *(const bf16x8*)(inbf + (size_t)c1 * 128 + fl * 8);
#pragma unroll
            for (int k = 0; k < 8; ++k)
                acc[k] += bf2f((unsigned short)a0[k]) + bf2f((unsigned short)a1[k]);
        }
        if (j < end) {
            const int c0 = col[j];
            bf16x8 a0 = *(const bf16x8*)(inbf + (size_t)c0 * 128 + fl * 8);
#pragma unroll
            for (int k = 0; k < 8; ++k) acc[k] += bf2f((unsigned short)a0[k]);
        }

#pragma unroll
        for (int v = 0; v < 8; ++v) {
            acc[v] += __shfl_down(acc[v], 32);
            acc[v] += __shfl_down(acc[v], 16);
        }

        if (quarter == 0) {
            float r[8];
#pragma unroll
            for (int v = 0; v < 8; ++v) {
                float t = dv * acc[v];
                if constexpr (HAS_BIAS) t += bias[fl * 8 + v];
                if constexpr (RELU) t = fmaxf(t, 0.0f);
                r[v] = t;
            }
            *(float4*)(out + (size_t)d * 128 + fl * 8)     = make_float4(r[0], r[1], r[2], r[3]);
            *(float4*)(out + (size_t)d * 128 + fl * 8 + 4) = make_float4(r[4], r[5], r[6], r[7]);
        }
    }
}

// F=64: wave per dst, GRID-STRIDE; EIGHTH-wave (8 lanes x 16B = one 128B line)
// per edge; 2-deep unroll -> 16 gathers in flight per wave.
// Optional premultiplied bf16 mirror of the OUTPUT (for a following aggregate-first layer).
template <bool RELU, bool HAS_BIAS, bool WRITE_BF>
__global__ __launch_bounds__(256) void agg64_kernel(const float* __restrict__ in32,
                                                    const unsigned short* __restrict__ inbf,
                                                    float* __restrict__ out,
                                                    unsigned short* __restrict__ outbf,
                                                    const int* __restrict__ rp,
                                                    const unsigned short* __restrict__ col,
                                                    const float* __restrict__ dinv,
                                                    const float* __restrict__ bias) {
    const int wave = threadIdx.x >> 6;
    const int lane = threadIdx.x & 63;
    const int eighth = lane >> 3;    // 0..7 : which edge of a group of 8
    const int fl = lane & 7;         // 8 lanes x 8 features = 64
    const int dstride = gridDim.x * 4;

    for (int d = blockIdx.x * 4 + wave; d < NNODES; d += dstride) {
        const float dv = dinv[d];

        float acc[8] = {0.f, 0.f, 0.f, 0.f, 0.f, 0.f, 0.f, 0.f};
        if (eighth == 0) {
            float4 s0 = *(const float4*)(in32 + (size_t)d * 64 + fl * 8);
            float4 s1 = *(const float4*)(in32 + (size_t)d * 64 + fl * 8 + 4);
            acc[0] = dv * s0.x; acc[1] = dv * s0.y; acc[2] = dv * s0.z; acc[3] = dv * s0.w;
            acc[4] = dv * s1.x; acc[5] = dv * s1.y; acc[6] = dv * s1.z; acc[7] = dv * s1.w;
        }

        int j = rp[d] + eighth;
        const int end = rp[d + 1];
        for (; j + 8 < end; j += 16) {
            const int c0 = col[j], c1 = col[j + 8];
            bf16x8 a0 = *(const bf16x8*)(inbf + (size_t)c0 * 64 + fl * 8);
            bf16x8 a1 = *(const bf16x8*)(inbf + (size_t)c1 * 64 + fl * 8);
#pragma unroll
            for (int k = 0; k < 8; ++k)
                acc[k] += bf2f((unsigned short)a0[k]) + bf2f((unsigned short)a1[k]);
        }
        if (j < end) {
            const int c0 = col[j];
            bf16x8 a0 = *(const bf16x8*)(inbf + (size_t)c0 * 64 + fl * 8);
#pragma unroll
            for (int k = 0; k < 8; ++k) acc[k] += bf2f((unsigned short)a0[k]);
        }

#pragma unroll
        for (int v = 0; v < 8; ++v) {
            acc[v] += __shfl_down(acc[v], 32);
            acc[v] += __shfl_down(acc[v], 16);
            acc[v] += __shfl_down(acc[v], 8);
        }

        if (eighth == 0) {
            float r[8];
#pragma unroll
            for (int v = 0; v < 8; ++v) {
                float t = dv * acc[v];
                if constexpr (HAS_BIAS) t += bias[fl * 8 + v];
                if constexpr (RELU) t = fmaxf(t, 0.0f);
                r[v] = t;
            }
            *(float4*)(out + (size_t)d * 64 + fl * 8)     = make_float4(r[0], r[1], r[2], r[3]);
            *(float4*)(out + (size_t)d * 64 + fl * 8 + 4) = make_float4(r[4], r[5], r[6], r[7]);
            if constexpr (WRITE_BF) {
                ushort4 h0, h1;
                h0.x = f2bf(dv * r[0]); h0.y = f2bf(dv * r[1]);
                h0.z = f2bf(dv * r[2]); h0.w = f2bf(dv * r[3]);
                h1.x = f2bf(dv * r[4]); h1.y = f2bf(dv * r[5]);
                h1.z = f2bf(dv * r[6]); h1.w = f2bf(dv * r[7]);
                *(ushort4*)(outbf + (size_t)d * 64 + fl * 8)     = h0;
                *(ushort4*)(outbf + (size_t)d * 64 + fl * 8 + 4) = h1;
            }
        }
    }
}

// ---------------- weight repack: W[K][M] fp32 -> split-bf16 fragment order ----
// Also zeroes an auxiliary int buffer (gcur) in the same dispatch.

template <int K, int M>
__global__ __launch_bounds__(256) void repack_kernel(const float* __restrict__ W,
                                                     unsigned short* __restrict__ hi,
                                                     unsigned short* __restrict__ lo,
                                                     int* __restrict__ zbuf, int zn) {
    int i = blockIdx.x * 256 + threadIdx.x;
    if (i < zn) zbuf[i] = 0;
    if (i >= K * M) return;
    const int k = i / M, n = i % M;
    constexpr int KS = K / 32;
    const int cb = n >> 7;
    const int ct = (n >> 4) & 7;
    const int ln = ((k >> 3) & 3) * 16 + (n & 15);
    const int j  = k & 7;
    const int ks = k >> 5;
    const size_t o = ((((size_t)cb * KS + ks) * 8 + ct) * 64 + ln) * 8 + j;
    const float f = W[i];
    const unsigned short h = f2bf(f);
    hi[o] = h;
    lo[o] = f2bf(f - bf2f(h));
}

// ---------------- split-bf16 MFMA GEMM (round-1 proven form) ----------------
// BM=64: 4 waves in 1x4, each 64x32. bf mirror premultiplied by dinv[row].

template <int K, int M, int BM, bool BIAS_RELU, bool WRITE_BF>
__global__ __launch_bounds__(256) void mfma_gemm_kernel(const float* __restrict__ A,
                                                        const unsigned short* __restrict__ Whi,
                                                        const unsigned short* __restrict__ Wlo,
                                                        const float* __restrict__ bias,
                                                        float* __restrict__ C,
                                                        unsigned short* __restrict__ Cbf,
                                                        const float* __restrict__ dinv) {
    constexpr int KS = K / 32;
    constexpr int ASZ = BM * 64;
    constexpr int CI = (BM == 128) ? 4 : 2;
    __shared__ char lds[2 * ASZ + 16384];
    char* Ahi = lds;
    char* Alo = lds + ASZ;
    char* Bhi = lds + 2 * ASZ;
    char* Blo = lds + 2 * ASZ + 8192;

    const int t = threadIdx.x;
    const int lane = t & 63;
    const int w = t >> 6;
    const int wr = (BM == 128) ? (w >> 1) : 0;
    const int wc = (BM == 128) ? (w & 1) : w;
    const int r0 = blockIdx.x * BM;
    const int n0 = blockIdx.y * 128;

    const unsigned short* bhg = Whi + (size_t)blockIdx.y * KS * 4096;
    const unsigned short* blg = Wlo + (size_t)blockIdx.y * KS * 4096;

    f32x4 acc[4][CI];
#pragma unroll
    for (int i = 0; i < 4; ++i)
#pragma unroll
        for (int j = 0; j < CI; ++j) acc[i][j] = (f32x4){0.f, 0.f, 0.f, 0.f};

    for (int ks = 0; ks < KS; ++ks) {
        const int k0 = ks * 32;

        {
            const char* gh = (const char*)(bhg + (size_t)ks * 4096);
            const char* gl = (const char*)(blg + (size_t)ks * 4096);
#pragma unroll
            for (int c = 0; c < 2; ++c) {
                const int ct = w * 2 + c;
                __builtin_amdgcn_global_load_lds(
                    (const __attribute__((address_space(1))) void*)(gh + ct * 1024 + lane * 16),
                    (__attribute__((address_space(3))) void*)(Bhi + ct * 1024), 16, 0, 0);
                __builtin_amdgcn_global_load_lds(
                    (const __attribute__((address_space(1))) void*)(gl + ct * 1024 + lane * 16),
                    (__attribute__((address_space(3))) void*)(Blo + ct * 1024), 16, 0, 0);
            }
        }

        float4 av[BM / 32];
#pragma unroll
        for (int i = 0; i < BM / 32; ++i) {
            const int q = t + i * 256;
            const int row = q >> 3;
            const int kq = (q & 7) * 4;
            const int gr = r0 + row;
            float4 v = make_float4(0.f, 0.f, 0.f, 0.f);
            if (gr < NNODES) v = *(const float4*)(A + (size_t)gr * K + k0 + kq);
            av[i] = v;
        }
#pragma unroll
        for (int i = 0; i < BM / 32; ++i) {
            const int q = t + i * 256;
            const int row = q >> 3;
            const int kq = (q & 7) * 4;
            const int rt = row >> 4, m = row & 15, quad = kq >> 3, j0 = kq & 7;
            const int off = rt * 1024 + (quad * 16 + m) * 16 + j0 * 2;
            const float4 v = av[i];
            ushort4 h, l;
            h.x = f2bf(v.x); l.x = f2bf(v.x - bf2f(h.x));
            h.y = f2bf(v.y); l.y = f2bf(v.y - bf2f(h.y));
            h.z = f2bf(v.z); l.z = f2bf(v.z - bf2f(h.z));
            h.w = f2bf(v.w); l.w = f2bf(v.w - bf2f(h.w));
            *(ushort4*)(Ahi + off) = h;
            *(ushort4*)(Alo + off) = l;
        }
        __syncthreads();

        bf16x8 ah[4], al[4], bh[CI], bl[CI];
#pragma unroll
        for (int i = 0; i < 4; ++i) {
            ah[i] = *(const bf16x8*)(Ahi + (wr * 4 + i) * 1024 + lane * 16);
            al[i] = *(const bf16x8*)(Alo + (wr * 4 + i) * 1024 + lane * 16);
        }
#pragma unroll
        for (int j = 0; j < CI; ++j) {
            bh[j] = *(const bf16x8*)(Bhi + (wc * CI + j) * 1024 + lane * 16);
            bl[j] = *(const bf16x8*)(Blo + (wc * CI + j) * 1024 + lane * 16);
        }
#pragma unroll
        for (int i = 0; i < 4; ++i)
#pragma unroll
            for (int j = 0; j < CI; ++j) {
                acc[i][j] = __builtin_amdgcn_mfma_f32_16x16x32_bf16(ah[i], bh[j], acc[i][j], 0, 0, 0);
                acc[i][j] = __builtin_amdgcn_mfma_f32_16x16x32_bf16(ah[i], bl[j], acc[i][j], 0, 0, 0);
                acc[i][j] = __builtin_amdgcn_mfma_f32_16x16x32_bf16(al[i], bh[j], acc[i][j], 0, 0, 0);
            }
        __syncthreads();
    }

    const int quad = lane >> 4;
    const int cl = lane & 15;
#pragma unroll
    for (int i = 0; i < 4; ++i) {
#pragma unroll
        for (int j = 0; j < CI; ++j) {
            const int colg = n0 + wc * (CI * 16) + j * 16 + cl;
            float bv = 0.f;
            if constexpr (BIAS_RELU) bv = bias[colg];
#pragma unroll
            for (int r = 0; r < 4; ++r) {
                const int rowg = r0 + wr * 64 + i * 16 + quad * 4 + r;
                if (rowg < NNODES) {
                    float v = acc[i][j][r] + bv;
                    if constexpr (BIAS_RELU) v = fmaxf(v, 0.f);
                    C[(size_t)rowg * M + colg] = v;
                    if constexpr (WRITE_BF) Cbf[(size_t)rowg * M + colg] = f2bf(dinv[rowg] * v);
                }
            }
        }
    }
}

// ---------------- fp32 register-tiled GEMM ----------------

template <int BM, int BN, int BK, int TM, int TN, bool HAS_BIAS, bool RELU, bool WRITE_BF>
__global__ __launch_bounds__(256) void gemm_kernel(const float* __restrict__ A,
                                                   const float* __restrict__ W,
                                                   const float* __restrict__ bias,
                                                   float* __restrict__ C,
                                                   unsigned short* __restrict__ Cbf,
                                                   const float* __restrict__ dinv,
                                                   int Nrows, int K, int M) {
    constexpr int TX = BN / TN;
    constexpr int TY = BM / TM;
    static_assert(TX * TY == 256, "thread grid must be 256");
    constexpr int A_LOADS = (BM * BK) / (256 * 4);
    constexpr int W_LOADS = (BN * BK) / (256 * 4);
    static_assert(A_LOADS >= 1 && W_LOADS >= 1, "tile too small");

    const int tid = threadIdx.x;
    const int tx = tid % TX;
    const int ty = tid / TX;
    const int r0 = blockIdx.x * BM;
    const int c0 = blockIdx.y * BN;

    __shared__ float As[BK][BM + 4];
    __shared__ float Ws[BK][BN];

    float acc[TM][TN] = {};

    for (int k0 = 0; k0 < K; k0 += BK) {
#pragma unroll
        for (int l = 0; l < A_LOADS; ++l) {
            const int idx = tid + l * 256;
            const int row = idx / (BK / 4);
            const int kq = idx % (BK / 4);
            float4 v = make_float4(0.f, 0.f, 0.f, 0.f);
            const int gr = r0 + row;
            if (gr < Nrows) v = *(const float4*)(A + (size_t)gr * K + k0 + kq * 4);
            As[kq * 4 + 0][row] = v.x;
            As[kq * 4 + 1][row] = v.y;
            As[kq * 4 + 2][row] = v.z;
            As[kq * 4 + 3][row] = v.w;
        }
#pragma unroll
        for (int l = 0; l < W_LOADS; ++l) {
            const int idx = tid + l * 256;
            const int kk = idx / (BN / 4);
            const int cq = idx % (BN / 4);
            const int gc = c0 + cq * 4;
            float4 v;
            const float* wrow = W + (size_t)(k0 + kk) * M;
            if (gc + 3 < M) {
                v = *(const float4*)(wrow + gc);
            } else {
                v.x = (gc + 0 < M) ? wrow[gc + 0] : 0.f;
                v.y = (gc + 1 < M) ? wrow[gc + 1] : 0.f;
                v.z = (gc + 2 < M) ? wrow[gc + 2] : 0.f;
                v.w = (gc + 3 < M) ? wrow[gc + 3] : 0.f;
            }
            *(float4*)&Ws[kk][cq * 4] = v;
        }
        __syncthreads();

#pragma unroll
        for (int kk = 0; kk < BK; ++kk) {
            float a[TM], b[TN];
#pragma unroll
            for (int i = 0; i < TM; ++i) a[i] = As[kk][ty * TM + i];
#pragma unroll
            for (int j = 0; j < TN; ++j) b[j] = Ws[kk][tx * TN + j];
#pragma unroll
            for (int i = 0; i < TM; ++i)
#pragma unroll
                for (int j = 0; j < TN; ++j) acc[i][j] += a[i] * b[j];
        }
        __syncthreads();
    }

#pragma unroll
    for (int i = 0; i < TM; ++i) {
        const int gr = r0 + ty * TM + i;
        if (gr >= Nrows) continue;
        const float dvr = WRITE_BF ? dinv[gr] : 0.f;
#pragma unroll
        for (int j = 0; j < TN; ++j) {
            const int gc = c0 + tx * TN + j;
            if (gc >= M) continue;
            float v = acc[i][j];
            if constexpr (HAS_BIAS) v += bias[gc];
            if constexpr (RELU) v = fmaxf(v, 0.0f);
            C[(size_t)gr * M + gc] = v;
            if constexpr (WRITE_BF) Cbf[(size_t)gr * M + gc] = f2bf(dvr * v);
        }
    }
}

// ---------------- launch ----------------

extern "C" void kernel_launch(void* const* d_in, const int* in_sizes, int n_in,
                              void* d_out, int out_size, void* d_ws, size_t ws_size,
                              hipStream_t stream) {
    const float* x  = (const float*)d_in[0];
    const int* ei   = (const int*)d_in[1];
    const float* W1 = (const float*)d_in[2];
    const float* b1 = (const float*)d_in[3];
    const float* W2 = (const float*)d_in[4];
    const float* b2 = (const float*)d_in[5];
    const float* W3 = (const float*)d_in[6];
    const float* b3 = (const float*)d_in[7];
    const float* W4 = (const float*)d_in[8];
    const float* b4 = (const float*)d_in[9];
    float* out = (float*)d_out;
    const int* esrc = ei;
    const int* edst = ei + NEDGES;

    char* w = (char*)d_ws;
    auto alloc = [&](size_t bytes) -> void* {
        void* p = (void*)w;
        w += (bytes + 255) & ~(size_t)255;
        return p;
    };
    int* rp     = (int*)alloc((size_t)(NNODES + 1) * 4);
    unsigned short* col = (unsigned short*)alloc((size_t)NEDGES * 2);
    float* dinv = (float*)alloc((size_t)NNODES * 4);
    int* gcur   = (int*)alloc((size_t)NB * 4);
    unsigned* gpk = (unsigned*)alloc((size_t)NB * BUCKCAP * 4);   // padded buckets
    unsigned short* W1hi = (unsigned short*)alloc((size_t)128 * 256 * 2);
    unsigned short* W1lo = (unsigned short*)alloc((size_t)128 * 256 * 2);
    unsigned short* W2hi = (unsigned short*)alloc((size_t)256 * 128 * 2);
    unsigned short* W2lo = (unsigned short*)alloc((size_t)256 * 128 * 2);
    float* B0   = (float*)alloc((size_t)NNODES * 256 * 4);
    float* B1   = (float*)alloc((size_t)NNODES * 128 * 4);
    float* B2   = (float*)alloc((size_t)NNODES * 128 * 4);
    unsigned short* xbf  = (unsigned short*)alloc((size_t)NNODES * 128 * 2);
    unsigned short* B1bf = (unsigned short*)alloc((size_t)NNODES * 128 * 2);
    unsigned short* B0bf = (unsigned short*)alloc((size_t)NNODES * 64 * 2);   // premult t3 mirror
    unsigned short* B3bf = (unsigned short*)alloc((size_t)NNODES * 64 * 2);   // premult h3 mirror

    // weight repack (first one also zeroes gcur)
    repack_kernel<128, 256><<<(128 * 256 + 255) / 256, 256, 0, stream>>>(W1, W1hi, W1lo, gcur, NB);
    repack_kernel<256, 128><<<(256 * 128 + 255) / 256, 256, 0, stream>>>(W2, W2hi, W2lo, nullptr, 0);

    // bucketed CSR build (2 dispatches) — produces rp, col16, dinv
    scatter_direct_kernel<<<SCAT_NBLK, 256, 0, stream>>>(esrc, edst, gcur, gpk);
    csr_fill2_kernel<<<NB, 256, 0, stream>>>(gpk, gcur, rp, dinv, col);

    // x mirror premultiplied by dinv (needs dinv)
    cvt_kernel<<<(NNODES * 128 / 4 + 255) / 256, 256, 0, stream>>>(x, dinv, xbf, NNODES * 128 / 4);

    const int rowBlks64 = (NNODES + 63) / 64;   // 782

    // Layer 1: aggregate first (dim 128), then MFMA GEMM 128->256 (+bias+relu)
    agg128_kernel<false, false><<<AGG_BLOCKS, 256, 0, stream>>>(x, xbf, B2, rp, col, dinv, nullptr);
    mfma_gemm_kernel<128, 256, 64, true, false>
        <<<dim3(rowBlks64, 2), 256, 0, stream>>>(B2, W1hi, W1lo, b1, B0, nullptr, nullptr);

    // Layer 2: MFMA GEMM 256->128 (emit premult bf16 mirror), then aggregate (+bias+relu)
    mfma_gemm_kernel<256, 128, 64, false, true>
        <<<dim3(rowBlks64, 1), 256, 0, stream>>>(B0, W2hi, W2lo, nullptr, B1, B1bf, dinv);
    agg128_kernel<true, true><<<AGG_BLOCKS, 256, 0, stream>>>(B1, B1bf, B2, rp, col, dinv, b2);

    // Layer 3: fp32 GEMM 128->64 (emit premult t3 mirror), aggregate (+bias+relu, emit premult h3 mirror)
    gemm_kernel<64, 64, 16, 4, 4, false, false, true>
        <<<dim3(rowBlks64, 1), 256, 0, stream>>>(B2, W3, nullptr, B0, B0bf, dinv, NNODES, 128, 64);
    agg64_kernel<true, true, true><<<AGG_BLOCKS, 256, 0, stream>>>(B0, B0bf, B1, B3bf, rp, col, dinv, b3);

    // Layer 4 (aggregate-first via linearity): pure agg64 on h3, then GEMM 64->40 (+bias) -> out
    agg64_kernel<false, false, false><<<AGG_BLOCKS, 256, 0, stream>>>(B1, B3bf, B2, nullptr, rp, col, dinv, nullptr);
    gemm_kernel<64, 64, 16, 4, 4, true, false, false>
        <<<dim3(rowBlks64, 1), 256, 0, stream>>>(B2, W4, b4, out, nullptr, nullptr, NNODES, 64, 40);
}